// Round 1
// baseline (4144.401 us; speedup 1.0000x reference)
//
#include <hip/hip_runtime.h>
#include <hip/hip_bf16.h>

// Problem constants (from reference)
#define SS   50     // sequence length
#define DD   300    // embedding dim
#define NH   15     // heads
#define HD   20     // per-head dim
#define QDIM 200    // additive attention dim

// LDS layout (bytes). All bf16 tiles have padded row strides for bank spread.
#define RS1 604     // row stride for 302-elem bf16 rows (uv/ue/Vc; also half of Q/K rows)
#define RS2 1208    // row stride for Q (Qc|Qp) and K (Ksum|Kc) rows
#define OFF_UV 0        // phase 0-1: uv bf16 [50][302]
#define OFF_UE 30200    // phase 0-1: ue bf16 [50][302]
#define OFF_Q  0        // phase 2+: Qcat bf16 rows 1208B (Qc @+0, Qp @+604); later ctx f32 chunks
#define OFF_K  60400    // Kcat bf16 rows 1208B (Ksum @+0, Kc @+604)
#define OFF_V  120800   // Vc bf16 [50][302]
#define OFF_T  60400    // pooling: t f32 [50][200] rows 800B (reuses K region)
#define OFF_ATT 151000  // per-wave attn row scratch: f32 [8][64]
#define OFF_IDS 153048  // int ids[50]
#define OFF_A   153248  // f32 a[64]
#define SM_TOTAL 153504

__device__ __forceinline__ float bflo(unsigned p){ return __uint_as_float(p << 16); }
__device__ __forceinline__ float bfhi(unsigned p){ return __uint_as_float(p & 0xffff0000u); }
__device__ __forceinline__ unsigned short f2bf(float x){
  unsigned u = __float_as_uint(x);
  return (unsigned short)((u + 0x7fffu + ((u >> 16) & 1u)) >> 16);
}
__device__ __forceinline__ unsigned packbf(float a, float b){
  return (unsigned)f2bf(a) | ((unsigned)f2bf(b) << 16);
}

// acc[NW] += IN[srow][k] * W[k][c0+j] over k=0..299.  IN is bf16 in LDS (row
// stride RS1); c0 must be wave-uniform (readfirstlane'd by caller) so W loads
// go through the scalar path.
template<int NW>
__device__ __forceinline__ void dotcols(const unsigned char* sm, unsigned inOff,
                                        const float* __restrict__ W, int ldw,
                                        int c0, int srow, float* acc){
  for (int k = 0; k < DD; k += 2){
    unsigned pr = *(const unsigned*)(sm + inOff + srow*RS1 + k*2);
    float a0 = bflo(pr), a1 = bfhi(pr);
    const float* w0 = W + (size_t)k*ldw + c0;
    const float* w1 = w0 + ldw;
    #pragma unroll
    for (int j = 0; j < NW; ++j){
      acc[j] = fmaf(a0, w0[j], acc[j]);
      acc[j] = fmaf(a1, w1[j], acc[j]);
    }
  }
}

__global__ __launch_bounds__(512) void user_enc_kernel(
    const int*   __restrict__ ids, const float* __restrict__ uv,
    const float* __restrict__ emb,
    const float* __restrict__ Wq,  const float* __restrict__ bq,
    const float* __restrict__ Wk,  const float* __restrict__ bk,
    const float* __restrict__ Wv,  const float* __restrict__ bv,
    const float* __restrict__ Wqp, const float* __restrict__ bqp,
    const float* __restrict__ Wkp, const float* __restrict__ bkp,
    const float* __restrict__ Wa,  const float* __restrict__ ba,
    const float* __restrict__ qa,  float* __restrict__ out)
{
  __shared__ __align__(16) unsigned char sm[SM_TOTAL];
  const int tid  = threadIdx.x;
  const int b    = blockIdx.x;
  const int w    = tid >> 6;
  const int lane = tid & 63;
  const int sl   = lane < SS ? lane : SS - 1;   // clamped row index
  const bool rowok = lane < SS;

  // ---------------- phase 0: load uv + gather ue (bf16 into LDS) -------------
  if (tid < SS) *(int*)(sm + OFF_IDS + tid*4) = ids[b*SS + tid];
  {
    const float* src = uv + (size_t)b * SS * DD;
    for (int i = tid; i < SS*DD/2; i += 512){
      float2 v = *(const float2*)(src + i*2);
      int s = (i*2)/DD, j = (i*2)%DD;
      *(unsigned*)(sm + OFF_UV + s*RS1 + j*2) = packbf(v.x, v.y);
    }
  }
  __syncthreads();
  for (int i = tid; i < SS*DD/2; i += 512){
    int s = (i*2)/DD, j = (i*2)%DD;
    int id = *(const int*)(sm + OFF_IDS + s*4);
    float2 v = *(const float2*)(emb + (size_t)id*DD + j);
    *(unsigned*)(sm + OFF_UE + s*RS1 + j*2) = packbf(v.x, v.y);
  }
  __syncthreads();

  // ---------------- phase 1: projections -------------------------------------
  // K: Ksum = uv@Wk+bk + ue@Wkp+bkp ; Kc = uv@Wk+bk  (cols 0..299, per-wave 8-strips)
  #pragma unroll
  for (int t = 0; t < 5; ++t){
    int cb = w + t*8;
    if (cb < 37){
      int c0 = __builtin_amdgcn_readfirstlane(cb*8);
      float aK[8] = {0,0,0,0,0,0,0,0}, aP[8] = {0,0,0,0,0,0,0,0};
      dotcols<8>(sm, OFF_UV, Wk,  DD, c0, sl, aK);
      dotcols<8>(sm, OFF_UE, Wkp, DD, c0, sl, aP);
      if (rowok){
        #pragma unroll
        for (int j = 0; j < 8; j += 2){
          float k0 = aK[j]   + bk[c0+j],   p0 = aP[j]   + bkp[c0+j];
          float k1 = aK[j+1] + bk[c0+j+1], p1 = aP[j+1] + bkp[c0+j+1];
          *(unsigned*)(sm + OFF_K + sl*RS2 + (c0+j)*2)       = packbf(k0+p0, k1+p1);
          *(unsigned*)(sm + OFF_K + sl*RS2 + RS1 + (c0+j)*2) = packbf(k0, k1);
        }
      }
    }
  }
  if (w == 5){ // tail cols 296..299
    const int c0 = 296;
    float aK[4] = {0,0,0,0}, aP[4] = {0,0,0,0};
    dotcols<4>(sm, OFF_UV, Wk,  DD, c0, sl, aK);
    dotcols<4>(sm, OFF_UE, Wkp, DD, c0, sl, aP);
    if (rowok){
      #pragma unroll
      for (int j = 0; j < 4; j += 2){
        float k0 = aK[j]   + bk[c0+j],   p0 = aP[j]   + bkp[c0+j];
        float k1 = aK[j+1] + bk[c0+j+1], p1 = aP[j+1] + bkp[c0+j+1];
        *(unsigned*)(sm + OFF_K + sl*RS2 + (c0+j)*2)       = packbf(k0+p0, k1+p1);
        *(unsigned*)(sm + OFF_K + sl*RS2 + RS1 + (c0+j)*2) = packbf(k0, k1);
      }
    }
  }
  // V
  #pragma unroll
  for (int t = 0; t < 5; ++t){
    int cb = w + t*8;
    if (cb < 37){
      int c0 = __builtin_amdgcn_readfirstlane(cb*8);
      float av[8] = {0,0,0,0,0,0,0,0};
      dotcols<8>(sm, OFF_UV, Wv, DD, c0, sl, av);
      if (rowok){
        #pragma unroll
        for (int j = 0; j < 8; j += 2)
          *(unsigned*)(sm + OFF_V + sl*RS1 + (c0+j)*2) =
              packbf(av[j] + bv[c0+j], av[j+1] + bv[c0+j+1]);
      }
    }
  }
  if (w == 5){
    const int c0 = 296;
    float av[4] = {0,0,0,0};
    dotcols<4>(sm, OFF_UV, Wv, DD, c0, sl, av);
    if (rowok){
      #pragma unroll
      for (int j = 0; j < 4; j += 2)
        *(unsigned*)(sm + OFF_V + sl*RS1 + (c0+j)*2) =
            packbf(av[j] + bv[c0+j], av[j+1] + bv[c0+j+1]);
    }
  }
  // Q: compute into registers (uv/ue still live), write to LDS after barrier.
  float qc[5][8], qp[5][8], qct[4], qpt[4];
  #pragma unroll
  for (int t = 0; t < 5; ++t){
    int cb = w + t*8;
    if (cb < 37){
      int c0 = __builtin_amdgcn_readfirstlane(cb*8);
      #pragma unroll
      for (int j = 0; j < 8; ++j){ qc[t][j] = 0.f; qp[t][j] = 0.f; }
      dotcols<8>(sm, OFF_UV, Wq,  DD, c0, sl, qc[t]);
      dotcols<8>(sm, OFF_UE, Wqp, DD, c0, sl, qp[t]);
      #pragma unroll
      for (int j = 0; j < 8; ++j){ qc[t][j] += bq[c0+j]; qp[t][j] += bqp[c0+j]; }
    }
  }
  if (w == 5){
    const int c0 = 296;
    #pragma unroll
    for (int j = 0; j < 4; ++j){ qct[j] = 0.f; qpt[j] = 0.f; }
    dotcols<4>(sm, OFF_UV, Wq,  DD, c0, sl, qct);
    dotcols<4>(sm, OFF_UE, Wqp, DD, c0, sl, qpt);
    #pragma unroll
    for (int j = 0; j < 4; ++j){ qct[j] += bq[c0+j]; qpt[j] += bqp[c0+j]; }
  }
  __syncthreads();
  #pragma unroll
  for (int t = 0; t < 5; ++t){
    int cb = w + t*8;
    if (cb < 37 && rowok){
      int c0 = cb*8;
      #pragma unroll
      for (int j = 0; j < 8; j += 2){
        *(unsigned*)(sm + OFF_Q + sl*RS2 + (c0+j)*2)       = packbf(qc[t][j], qc[t][j+1]);
        *(unsigned*)(sm + OFF_Q + sl*RS2 + RS1 + (c0+j)*2) = packbf(qp[t][j], qp[t][j+1]);
      }
    }
  }
  if (w == 5 && rowok){
    const int c0 = 296;
    #pragma unroll
    for (int j = 0; j < 4; j += 2){
      *(unsigned*)(sm + OFF_Q + sl*RS2 + (c0+j)*2)       = packbf(qct[j], qct[j+1]);
      *(unsigned*)(sm + OFF_Q + sl*RS2 + RS1 + (c0+j)*2) = packbf(qpt[j], qpt[j+1]);
    }
  }
  __syncthreads();

  // ---------------- phase 2: attention (one wave per (h,q) pair) -------------
  const float rscale = 0.1290994449f;  // 1/sqrt(3*DK)
  for (int p = w; p < NH*SS; p += 8){
    int h = p / SS, q = p - h*SS;
    int hb = h * 40;                    // byte offset of head chunk (20 bf16)
    float sc = -INFINITY;
    {
      float acc = 0.f;
      #pragma unroll
      for (int d2 = 0; d2 < HD; d2 += 2){
        unsigned qc2 = *(const unsigned*)(sm + OFF_Q + q*RS2 + hb + d2*2);
        unsigned qp2 = *(const unsigned*)(sm + OFF_Q + q*RS2 + RS1 + hb + d2*2);
        unsigned ks2 = *(const unsigned*)(sm + OFF_K + sl*RS2 + hb + d2*2);
        unsigned kc2 = *(const unsigned*)(sm + OFF_K + sl*RS2 + RS1 + hb + d2*2);
        acc += bflo(qc2)*bflo(ks2) + bfhi(qc2)*bfhi(ks2)
             + bflo(qp2)*bflo(kc2) + bfhi(qp2)*bfhi(kc2);
      }
      if (rowok) sc = acc * rscale;
    }
    float m = sc;
    #pragma unroll
    for (int off = 32; off; off >>= 1) m = fmaxf(m, __shfl_xor(m, off));
    float e = rowok ? __expf(sc - m) : 0.f;
    float ssum = e;
    #pragma unroll
    for (int off = 32; off; off >>= 1) ssum += __shfl_xor(ssum, off);
    float attn = e / ssum;
    *(float*)(sm + OFF_ATT + (w*64 + lane)*4) = attn;
    asm volatile("s_waitcnt lgkmcnt(0)" ::: "memory");
    if (lane < HD){
      float cacc = 0.f;
      for (int kk = 0; kk < SS; ++kk){
        float av = *(const float*)(sm + OFF_ATT + (w*64 + kk)*4);
        unsigned short vv = *(const unsigned short*)(sm + OFF_V + kk*RS1 + (h*HD + lane)*2);
        cacc = fmaf(av, __uint_as_float(((unsigned)vv) << 16), cacc);
      }
      // ctx[q][h*20+d] written in-place over this pair's (dead) Q chunk:
      // d<10 -> Qc slot bytes, d>=10 -> Qp slot bytes (20 f32 == 40 bf16).
      int d = lane;
      unsigned off2 = q*RS2 + (unsigned)(d < 10 ? hb + d*4 : RS1 + hb + (d-10)*4);
      *(float*)(sm + OFF_Q + off2) = cacc;
    }
  }
  __syncthreads();

  // ---------------- phase 3: additive pooling --------------------------------
  // t[s][j] = tanh(ctx[s]·Wa[:,j] + ba[j])  -> OFF_T (f32 rows 800B)
  #pragma unroll
  for (int t = 0; t < 4; ++t){
    int cb = w + t*8;
    if (cb < 25){
      int c0 = __builtin_amdgcn_readfirstlane(cb*8);
      float acc[8];
      #pragma unroll
      for (int j = 0; j < 8; ++j) acc[j] = ba[c0+j];
      for (int h = 0; h < NH; ++h){
        for (int d = 0; d < HD; ++d){
          unsigned coff = sl*RS2 + (unsigned)(d < 10 ? h*40 + d*4 : RS1 + h*40 + (d-10)*4);
          float cv = *(const float*)(sm + OFF_Q + coff);
          const float* wrow = Wa + (size_t)(h*HD + d)*QDIM + c0;
          #pragma unroll
          for (int j = 0; j < 8; ++j) acc[j] = fmaf(cv, wrow[j], acc[j]);
        }
      }
      if (rowok){
        #pragma unroll
        for (int j = 0; j < 8; ++j)
          *(float*)(sm + OFF_T + sl*800 + (c0+j)*4) = tanhf(acc[j]);
      }
    }
  }
  __syncthreads();
  if (w == 0){
    float lg = -INFINITY;
    if (rowok){
      float acc = 0.f;
      for (int j = 0; j < QDIM; ++j)
        acc = fmaf(*(const float*)(sm + OFF_T + sl*800 + j*4), qa[j], acc);
      lg = acc;
    }
    float m = lg;
    #pragma unroll
    for (int off = 32; off; off >>= 1) m = fmaxf(m, __shfl_xor(m, off));
    float e = rowok ? __expf(lg - m) : 0.f;
    float ssum = e;
    #pragma unroll
    for (int off = 32; off; off >>= 1) ssum += __shfl_xor(ssum, off);
    *(float*)(sm + OFF_A + lane*4) = e / ssum;
  }
  __syncthreads();
  if (tid < DD){
    int d = tid;
    int h = d / HD, dd = d - h*HD;
    unsigned base = (unsigned)(dd < 10 ? h*40 + dd*4 : RS1 + h*40 + (dd-10)*4);
    float acc = 0.f;
    for (int s = 0; s < SS; ++s){
      float av = *(const float*)(sm + OFF_A + s*4);
      float cv = *(const float*)(sm + OFF_Q + s*RS2 + base);
      acc = fmaf(av, cv, acc);
    }
    out[(size_t)b*DD + d] = acc;
  }
}

extern "C" void kernel_launch(void* const* d_in, const int* in_sizes, int n_in,
                              void* d_out, int out_size, void* d_ws, size_t ws_size,
                              hipStream_t stream){
  (void)n_in; (void)d_ws; (void)ws_size; (void)out_size;
  const int*   ids = (const int*)  d_in[0];
  const float* uvp = (const float*)d_in[1];
  const float* emb = (const float*)d_in[2];
  const float* Wq  = (const float*)d_in[3];
  const float* bq  = (const float*)d_in[4];
  const float* Wk  = (const float*)d_in[5];
  const float* bk  = (const float*)d_in[6];
  const float* Wv  = (const float*)d_in[7];
  const float* bv  = (const float*)d_in[8];
  const float* Wqp = (const float*)d_in[9];
  const float* bqp = (const float*)d_in[10];
  const float* Wkp = (const float*)d_in[11];
  const float* bkp = (const float*)d_in[12];
  const float* Wa  = (const float*)d_in[13];
  const float* ba  = (const float*)d_in[14];
  const float* qa  = (const float*)d_in[15];
  const int nb = in_sizes[0] / SS;   // batch (1024)
  user_enc_kernel<<<nb, 512, 0, stream>>>(ids, uvp, emb, Wq, bq, Wk, bk, Wv, bv,
                                          Wqp, bqp, Wkp, bkp, Wa, ba, qa,
                                          (float*)d_out);
}

// Round 2
// 673.023 us; speedup vs baseline: 6.1579x; 6.1579x over previous
//
#include <hip/hip_runtime.h>
#include <hip/hip_bf16.h>

#define SS   50     // sequence length
#define DD   300    // embedding dim
#define NH   15     // heads
#define HD   20     // per-head dim
#define QDIM 200    // additive attention dim

// ---------------- LDS layout (bytes) ----------------
// phase 0-1: uv/ue bf16 [50][328] stride 656 (k-padded to 320 with zeros)
// phase 1 out: VT bf16 [300 d][52 keys] stride 104 ; K rows: Ksum@+0, Kc@+616, stride 1240
// phase 1 end: Qc over OFF_UV (stride 608), Qp over OFF_UE
// phase 2: ctx f32 overwrites Qc/Qp head-chunks in place
// phase 3: ctx-bf16 A-layout over OFF_K (stride 656); lg2d f32 [64][8] over OFF_VT
#define OFF_UV  0
#define OFF_UE  32800
#define OFF_K   65600
#define KCOFF   616
#define KSTRIDE 1240
#define OFF_VT  127600
#define OFF_ATT 158800
#define OFF_IDS 160848
#define OFF_A   161048
#define SM_TOTAL 161304

// ws (bf16 elements): 5 proj [304][320] + Wa [208][320]
#define WSEG  97280
#define WAOFF 486400
#define WTOT  552960

typedef __attribute__((ext_vector_type(8))) short bf8t;
typedef __attribute__((ext_vector_type(4))) float f4t;

__device__ __forceinline__ float bflo(unsigned p){ return __uint_as_float(p << 16); }
__device__ __forceinline__ float bfhi(unsigned p){ return __uint_as_float(p & 0xffff0000u); }
__device__ __forceinline__ unsigned short f2bf(float x){
  unsigned u = __float_as_uint(x);
  return (unsigned short)((u + 0x7fffu + ((u >> 16) & 1u)) >> 16);
}
__device__ __forceinline__ unsigned packbf(float a, float b){
  return (unsigned)f2bf(a) | ((unsigned)f2bf(b) << 16);
}

// ---------------- weight converter: f32 [300][N] -> bf16 [Npad][320] (B^T, zero-padded)
__global__ __launch_bounds__(256) void conv_weights(
    const float* __restrict__ Wq, const float* __restrict__ Wk,
    const float* __restrict__ Wv, const float* __restrict__ Wqp,
    const float* __restrict__ Wkp, const float* __restrict__ Wa,
    short* __restrict__ ws)
{
  int idx = blockIdx.x*256 + threadIdx.x;
  if (idx >= WTOT) return;
  float v = 0.f;
  if (idx < WAOFF){
    int seg = idx / WSEG, r = idx - seg*WSEG;
    int n = r / 320, k = r - n*320;
    const float* W = (seg==0)?Wq:(seg==1)?Wk:(seg==2)?Wv:(seg==3)?Wqp:Wkp;
    if (n < DD && k < DD) v = W[k*DD + n];
  } else {
    int r = idx - WAOFF;
    int n = r / 320, k = r - n*320;
    if (n < QDIM && k < DD) v = Wa[k*QDIM + n];
  }
  ws[idx] = (short)f2bf(v);
}

// ---------------- 10-step K-loop MFMA GEMM: acc += A(LDS,stride656) @ B(ws) ----
template<int NT, int NCTM>
__device__ __forceinline__ void gemm10(const unsigned char* sm, unsigned abase,
                                       const short* __restrict__ wt,
                                       int lane, int w, f4t (&acc)[NT][4])
{
  const int lm = lane & 15, lg = lane >> 4;
  #pragma unroll
  for (int step = 0; step < 10; ++step){
    bf8t a[4];
    #pragma unroll
    for (int rt = 0; rt < 4; ++rt)
      a[rt] = *(const bf8t*)(sm + abase + (unsigned)(rt*16 + lm)*656u + (unsigned)(step*32 + lg*8)*2u);
    #pragma unroll
    for (int t = 0; t < NT; ++t){
      int ct = w + t*8; if (ct > NCTM) ct = NCTM;
      bf8t bb = *(const bf8t*)(wt + (size_t)(ct*16 + lm)*320 + step*32 + lg*8);
      #pragma unroll
      for (int rt = 0; rt < 4; ++rt)
        acc[t][rt] = __builtin_amdgcn_mfma_f32_16x16x32_bf16(a[rt], bb, acc[t][rt], 0, 0, 0);
    }
  }
}

__device__ __forceinline__ void zero_acc(f4t (&acc)[3][4]){
  #pragma unroll
  for (int t = 0; t < 3; ++t)
    #pragma unroll
    for (int r = 0; r < 4; ++r) acc[t][r] = (f4t){0.f,0.f,0.f,0.f};
}

// write tiles (+bias, bf16) to row-major LDS: base + row*KSTRIDE + coff + col*2
__device__ __forceinline__ void writeK_tiles(unsigned char* sm, unsigned coff,
    const float* __restrict__ b1, const float* __restrict__ b2,
    int lane, int w, f4t (&acc)[3][4])
{
  const int lm = lane & 15, lg = lane >> 4;
  #pragma unroll
  for (int t = 0; t < 3; ++t){
    int ct = w + t*8; if (ct > 18) ct = 18;
    int col = ct*16 + lm;
    if (col < DD){
      float bb = b1[col] + (b2 ? b2[col] : 0.f);
      #pragma unroll
      for (int rt = 0; rt < 4; ++rt)
        #pragma unroll
        for (int i = 0; i < 4; ++i){
          int row = rt*16 + lg*4 + i;
          if (row < SS)
            *(unsigned short*)(sm + OFF_K + (unsigned)row*KSTRIDE + coff + (unsigned)col*2) =
                f2bf(acc[t][rt][i] + bb);
        }
    }
  }
}

__global__ __launch_bounds__(512) void user_enc_kernel(
    const int*   __restrict__ ids, const float* __restrict__ uv,
    const float* __restrict__ emb,
    const float* __restrict__ bq, const float* __restrict__ bk,
    const float* __restrict__ bv, const float* __restrict__ bqp,
    const float* __restrict__ bkp,
    const float* __restrict__ ba, const float* __restrict__ qa,
    const short* __restrict__ wsb, float* __restrict__ out)
{
  __shared__ __align__(16) unsigned char sm[SM_TOTAL];
  const int tid  = threadIdx.x;
  const int b    = blockIdx.x;
  const int w    = tid >> 6;
  const int lane = tid & 63;
  const int lm   = lane & 15, lg = lane >> 4;
  const int sl   = lane < SS ? lane : SS - 1;
  const bool rowok = lane < SS;

  const short* wqT  = wsb;
  const short* wkT  = wsb + WSEG;
  const short* wvT  = wsb + 2*WSEG;
  const short* wqpT = wsb + 3*WSEG;
  const short* wkpT = wsb + 4*WSEG;
  const short* waT  = wsb + WAOFF;

  // ---------------- phase 0: stage uv + gathered ue as bf16 (zero k-pad) -----
  if (tid < SS) *(int*)(sm + OFF_IDS + tid*4) = ids[(size_t)b*SS + tid];
  __syncthreads();
  {
    const float* src = uv + (size_t)b*SS*DD;
    for (int i = tid; i < SS*160; i += 512){
      int s = i/160, j2 = i - s*160;
      unsigned val = 0;
      if (j2 < 150){ float2 v = *(const float2*)(src + s*DD + j2*2); val = packbf(v.x, v.y); }
      *(unsigned*)(sm + OFF_UV + (unsigned)s*656 + (unsigned)j2*4) = val;
    }
    for (int i = tid; i < SS*160; i += 512){
      int s = i/160, j2 = i - s*160;
      unsigned val = 0;
      if (j2 < 150){
        int id = *(const int*)(sm + OFF_IDS + s*4);
        float2 v = *(const float2*)(emb + (size_t)id*DD + j2*2);
        val = packbf(v.x, v.y);
      }
      *(unsigned*)(sm + OFF_UE + (unsigned)s*656 + (unsigned)j2*4) = val;
    }
    // zero VT pad key-columns 50,51
    for (int i = tid; i < 600; i += 512)
      *(unsigned short*)(sm + OFF_VT + (unsigned)(i>>1)*104 + (50 + (i&1))*2) = 0;
  }
  __syncthreads();

  // ---------------- phase 1: MFMA projections --------------------------------
  f4t acc[3][4];
  // V -> VT (transposed store)
  zero_acc(acc);
  gemm10<3,18>(sm, OFF_UV, wvT, lane, w, acc);
  {
    #pragma unroll
    for (int t = 0; t < 3; ++t){
      int ct = w + t*8; if (ct > 18) ct = 18;
      int col = ct*16 + lm;
      if (col < DD){
        float bvv = bv[col];
        #pragma unroll
        for (int rt = 0; rt < 4; ++rt)
          #pragma unroll
          for (int i = 0; i < 4; ++i){
            int row = rt*16 + lg*4 + i;
            if (row < SS)
              *(unsigned short*)(sm + OFF_VT + (unsigned)col*104 + (unsigned)row*2) =
                  f2bf(acc[t][rt][i] + bvv);
          }
      }
    }
  }
  // K: Kc = uv@Wk + bk ; Ksum = Kc + ue@Wkp + bkp
  zero_acc(acc);
  gemm10<3,18>(sm, OFF_UV, wkT, lane, w, acc);
  writeK_tiles(sm, KCOFF, bk, nullptr, lane, w, acc);
  gemm10<3,18>(sm, OFF_UE, wkpT, lane, w, acc);
  writeK_tiles(sm, 0, bk, bkp, lane, w, acc);
  // Q: compute into packed regs (uv/ue still live), write after barrier
  unsigned qcp[3][4][2], qpp[3][4][2];
  zero_acc(acc);
  gemm10<3,18>(sm, OFF_UV, wqT, lane, w, acc);
  #pragma unroll
  for (int t = 0; t < 3; ++t){
    int ct = w + t*8; if (ct > 18) ct = 18;
    int col = ct*16 + lm;
    float bb = (col < DD) ? bq[col] : 0.f;
    #pragma unroll
    for (int rt = 0; rt < 4; ++rt){
      qcp[t][rt][0] = packbf(acc[t][rt][0]+bb, acc[t][rt][1]+bb);
      qcp[t][rt][1] = packbf(acc[t][rt][2]+bb, acc[t][rt][3]+bb);
    }
  }
  zero_acc(acc);
  gemm10<3,18>(sm, OFF_UE, wqpT, lane, w, acc);
  #pragma unroll
  for (int t = 0; t < 3; ++t){
    int ct = w + t*8; if (ct > 18) ct = 18;
    int col = ct*16 + lm;
    float bb = (col < DD) ? bqp[col] : 0.f;
    #pragma unroll
    for (int rt = 0; rt < 4; ++rt){
      qpp[t][rt][0] = packbf(acc[t][rt][0]+bb, acc[t][rt][1]+bb);
      qpp[t][rt][1] = packbf(acc[t][rt][2]+bb, acc[t][rt][3]+bb);
    }
  }
  __syncthreads();   // all uv/ue reads done; V/K writes done
  #pragma unroll
  for (int t = 0; t < 3; ++t){
    int ct = w + t*8; if (ct > 18) ct = 18;
    int col = ct*16 + lm;
    if (col < DD){
      #pragma unroll
      for (int rt = 0; rt < 4; ++rt)
        #pragma unroll
        for (int i = 0; i < 4; ++i){
          int row = rt*16 + lg*4 + i;
          if (row < SS){
            *(unsigned short*)(sm + OFF_UV + (unsigned)row*608 + (unsigned)col*2) =
                (unsigned short)(qcp[t][rt][i>>1] >> (16*(i&1)));
            *(unsigned short*)(sm + OFF_UE + (unsigned)row*608 + (unsigned)col*2) =
                (unsigned short)(qpp[t][rt][i>>1] >> (16*(i&1)));
          }
        }
    }
  }
  __syncthreads();

  // ---------------- phase 2: attention (lane = key; per-head hoists) ---------
  const float rscale = 0.1290994449f;  // 1/sqrt(3*DK)
  for (int h = 0; h < NH; ++h){
    const int hb = h*40;
    uint2 ksv[5], kcv[5];
    #pragma unroll
    for (int j = 0; j < 5; ++j){
      ksv[j] = *(const uint2*)(sm + OFF_K + (unsigned)sl*KSTRIDE + hb + j*8);
      kcv[j] = *(const uint2*)(sm + OFF_K + (unsigned)sl*KSTRIDE + KCOFF + hb + j*8);
    }
    const int vrow = h*HD + (lane < HD ? lane : HD-1);
    uint2 vtv[13];
    #pragma unroll
    for (int j = 0; j < 13; ++j)
      vtv[j] = *(const uint2*)(sm + OFF_VT + (unsigned)vrow*104 + j*8);

    for (int q = w; q < SS; q += 8){
      float accs = 0.f;
      #pragma unroll
      for (int j = 0; j < 5; ++j){
        uint2 qc2 = *(const uint2*)(sm + OFF_UV + (unsigned)q*608 + hb + j*8);
        uint2 qp2 = *(const uint2*)(sm + OFF_UE + (unsigned)q*608 + hb + j*8);
        accs += bflo(qc2.x)*bflo(ksv[j].x) + bfhi(qc2.x)*bfhi(ksv[j].x)
              + bflo(qc2.y)*bflo(ksv[j].y) + bfhi(qc2.y)*bfhi(ksv[j].y)
              + bflo(qp2.x)*bflo(kcv[j].x) + bfhi(qp2.x)*bfhi(kcv[j].x)
              + bflo(qp2.y)*bflo(kcv[j].y) + bfhi(qp2.y)*bfhi(kcv[j].y);
      }
      float sc = rowok ? accs*rscale : -INFINITY;
      float m = sc;
      #pragma unroll
      for (int off = 32; off; off >>= 1) m = fmaxf(m, __shfl_xor(m, off));
      float e = rowok ? __expf(sc - m) : 0.f;
      float ssum = e;
      #pragma unroll
      for (int off = 32; off; off >>= 1) ssum += __shfl_xor(ssum, off);
      *(float*)(sm + OFF_ATT + (unsigned)(w*64 + lane)*4) = e / ssum;
      asm volatile("s_waitcnt lgkmcnt(0)" ::: "memory");
      if (lane < HD){
        float cacc = 0.f;
        #pragma unroll
        for (int c = 0; c < 13; ++c){
          float4 av = *(const float4*)(sm + OFF_ATT + (unsigned)w*256 + (unsigned)c*16);
          cacc += av.x*bflo(vtv[c].x) + av.y*bfhi(vtv[c].x)
                + av.z*bflo(vtv[c].y) + av.w*bfhi(vtv[c].y);
        }
        int d = lane;
        if (d < 10) *(float*)(sm + OFF_UV + (unsigned)q*608 + hb + d*4) = cacc;
        else        *(float*)(sm + OFF_UE + (unsigned)q*608 + hb + (d-10)*4) = cacc;
      }
    }
  }
  __syncthreads();

  // ---------------- phase 3: pooling ----------------------------------------
  // 3a: ctx f32 -> bf16 A-layout over OFF_K (stride 656, k-pad zeros)
  for (int i = tid; i < SS*160; i += 512){
    int s = i/160, j2 = i - s*160;
    unsigned val = 0;
    int c0 = j2*2;
    if (c0 < DD){
      int h = c0/HD, d0 = c0 - h*HD;
      unsigned bse = (d0 < 10) ? (OFF_UV + (unsigned)h*40 + (unsigned)d0*4)
                               : (OFF_UE + (unsigned)h*40 + (unsigned)(d0-10)*4);
      const float* p = (const float*)(sm + bse + (unsigned)s*608);
      val = packbf(p[0], p[1]);
    }
    *(unsigned*)(sm + OFF_K + (unsigned)s*656 + (unsigned)j2*4) = val;
  }
  __syncthreads();
  // 3b: t = tanh(ctx@Wa + ba); per-wave row-sums of t*qa -> lg2d[row][w]
  {
    f4t accp[2][4];
    #pragma unroll
    for (int t = 0; t < 2; ++t)
      #pragma unroll
      for (int r = 0; r < 4; ++r) accp[t][r] = (f4t){0.f,0.f,0.f,0.f};
    gemm10<2,12>(sm, OFF_K, waT, lane, w, accp);
    float part[4][4];
    #pragma unroll
    for (int rt = 0; rt < 4; ++rt)
      #pragma unroll
      for (int i = 0; i < 4; ++i) part[rt][i] = 0.f;
    #pragma unroll
    for (int t = 0; t < 2; ++t){
      int ct = w + t*8; if (ct > 12) ct = 12;
      bool valid = (t == 0) || (w < 5);
      int col = ct*16 + lm;
      float bav = (col < QDIM) ? ba[col] : 0.f;
      float qav = (valid && col < QDIM) ? qa[col] : 0.f;
      #pragma unroll
      for (int rt = 0; rt < 4; ++rt)
        #pragma unroll
        for (int i = 0; i < 4; ++i)
          part[rt][i] += tanhf(accp[t][rt][i] + bav) * qav;
    }
    #pragma unroll
    for (int off = 1; off <= 8; off <<= 1)
      #pragma unroll
      for (int rt = 0; rt < 4; ++rt)
        #pragma unroll
        for (int i = 0; i < 4; ++i)
          part[rt][i] += __shfl_xor(part[rt][i], off);
    if (lm == 0){
      #pragma unroll
      for (int rt = 0; rt < 4; ++rt)
        #pragma unroll
        for (int i = 0; i < 4; ++i){
          int row = rt*16 + lg*4 + i;
          if (row < SS) *(float*)(sm + OFF_VT + (unsigned)(row*8 + w)*4) = part[rt][i];
        }
    }
  }
  __syncthreads();
  if (w == 0){
    float lgv = -INFINITY;
    if (rowok){
      float s = 0.f;
      #pragma unroll
      for (int j = 0; j < 8; ++j) s += *(const float*)(sm + OFF_VT + (unsigned)(sl*8 + j)*4);
      lgv = s;
    }
    float m = lgv;
    #pragma unroll
    for (int off = 32; off; off >>= 1) m = fmaxf(m, __shfl_xor(m, off));
    float e = rowok ? __expf(lgv - m) : 0.f;
    float ssum = e;
    #pragma unroll
    for (int off = 32; off; off >>= 1) ssum += __shfl_xor(ssum, off);
    *(float*)(sm + OFF_A + lane*4) = e / ssum;
  }
  __syncthreads();
  // ---------------- phase 4: output -----------------------------------------
  if (tid < DD){
    int d = tid, h = d/HD, dd = d - h*HD;
    unsigned base = (dd < 10) ? (OFF_UV + (unsigned)h*40 + (unsigned)dd*4)
                              : (OFF_UE + (unsigned)h*40 + (unsigned)(dd-10)*4);
    float accv = 0.f;
    for (int s = 0; s < SS; ++s){
      float av = *(const float*)(sm + OFF_A + s*4);
      accv = fmaf(av, *(const float*)(sm + base + (unsigned)s*608), accv);
    }
    out[(size_t)b*DD + d] = accv;
  }
}

extern "C" void kernel_launch(void* const* d_in, const int* in_sizes, int n_in,
                              void* d_out, int out_size, void* d_ws, size_t ws_size,
                              hipStream_t stream){
  (void)n_in; (void)ws_size; (void)out_size;
  const int*   ids = (const int*)  d_in[0];
  const float* uvp = (const float*)d_in[1];
  const float* emb = (const float*)d_in[2];
  const float* Wq  = (const float*)d_in[3];
  const float* bq  = (const float*)d_in[4];
  const float* Wk  = (const float*)d_in[5];
  const float* bk  = (const float*)d_in[6];
  const float* Wv  = (const float*)d_in[7];
  const float* bv  = (const float*)d_in[8];
  const float* Wqp = (const float*)d_in[9];
  const float* bqp = (const float*)d_in[10];
  const float* Wkp = (const float*)d_in[11];
  const float* bkp = (const float*)d_in[12];
  const float* Wa  = (const float*)d_in[13];
  const float* ba  = (const float*)d_in[14];
  const float* qa  = (const float*)d_in[15];
  short* wsb = (short*)d_ws;

  conv_weights<<<(WTOT + 255)/256, 256, 0, stream>>>(Wq, Wk, Wv, Wqp, Wkp, Wa, wsb);

  const int nb = in_sizes[0] / SS;   // 1024
  user_enc_kernel<<<nb, 512, 0, stream>>>(ids, uvp, emb,
                                          bq, bk, bv, bqp, bkp, ba, qa,
                                          (const short*)wsb, (float*)d_out);
}

// Round 3
// 521.208 us; speedup vs baseline: 7.9515x; 1.2913x over previous
//
#include <hip/hip_runtime.h>
#include <hip/hip_bf16.h>

#define SS   50     // sequence length
#define DD   300    // embedding dim
#define NH   15     // heads
#define HD   20     // per-head dim
#define QDIM 200    // additive attention dim

// ---------------- LDS layout (bytes) ----------------
// Staging (phase 0-1): uv bf16 [50][328] @0 stride 656; ue @32800 (both die at batch writes)
// Attention (per head-batch of <=4 heads):
//   Qcat [50 q][4h x 48d bf16] stride 400 @ OFF_Q   ([Qc20|Qp20|8z] per head)
//   Kcat same layout           @ OFF_K              ([Ksum20|Kc20|8z])
//   VT   [92 rows=(hl*20+d)][64 keys bf16] stride 144 @ OFF_VT (zeroed per batch)
//   P    per-wave [32][64 keys bf16] stride 144 @ OFF_P + w*4608
//   ctx  bf16 [50][328] stride 656 @ OFF_CTX (accumulates across batches)
// Pooling: lg2d f32 [64][8] @ OFF_LG; a f32[64] @ OFF_A2
#define QKSTRIDE 400
#define OFF_Q    0
#define OFF_K    20000
#define OFF_VT   40000
#define VT_SZ    13248
#define OFF_P    53248
#define PBLK     4608
#define OFF_CTX  90112
#define OFF_LG   122912
#define OFF_A2   124960
#define OFF_IDS  125216
#define SM_TOTAL 132352   // covers ctx A-overread to row 63

#define OFF_UV 0
#define OFF_UE 32800

// ws (bf16 elements): 5 proj [304][320] + Wa [208][320]
#define WSEG  97280
#define WAOFF 486400
#define WTOT  552960

typedef __attribute__((ext_vector_type(8)))  short bf8t;
typedef __attribute__((ext_vector_type(4)))  float f4t;
typedef __attribute__((ext_vector_type(16))) float f16t;

__device__ __forceinline__ float bflo(unsigned p){ return __uint_as_float(p << 16); }
__device__ __forceinline__ float bfhi(unsigned p){ return __uint_as_float(p & 0xffff0000u); }
__device__ __forceinline__ unsigned short f2bf(float x){
  unsigned u = __float_as_uint(x);
  return (unsigned short)((u + 0x7fffu + ((u >> 16) & 1u)) >> 16);
}
__device__ __forceinline__ unsigned packbf(float a, float b){
  return (unsigned)f2bf(a) | ((unsigned)f2bf(b) << 16);
}
__device__ __forceinline__ f16t zero16(){
  f16t v;
  #pragma unroll
  for (int i = 0; i < 16; ++i) v[i] = 0.f;
  return v;
}

// ---------------- weight converter: f32 [300][N] -> bf16 [Npad][320] (B^T, zero-padded)
__global__ __launch_bounds__(256) void conv_weights(
    const float* __restrict__ Wq, const float* __restrict__ Wk,
    const float* __restrict__ Wv, const float* __restrict__ Wqp,
    const float* __restrict__ Wkp, const float* __restrict__ Wa,
    short* __restrict__ ws)
{
  int idx = blockIdx.x*256 + threadIdx.x;
  if (idx >= WTOT) return;
  float v = 0.f;
  if (idx < WAOFF){
    int seg = idx / WSEG, r = idx - seg*WSEG;
    int n = r / 320, k = r - n*320;
    const float* W = (seg==0)?Wq:(seg==1)?Wk:(seg==2)?Wv:(seg==3)?Wqp:Wkp;
    if (n < DD && k < DD) v = W[k*DD + n];
  } else {
    int r = idx - WAOFF;
    int n = r / 320, k = r - n*320;
    if (n < QDIM && k < DD) v = Wa[k*QDIM + n];
  }
  ws[idx] = (short)f2bf(v);
}

// ---------------- 10-step K-loop MFMA GEMM: acc += A(LDS,stride656) @ B(ws) ----
template<int NT, int NCTM>
__device__ __forceinline__ void gemm10(const unsigned char* sm, unsigned abase,
                                       const short* __restrict__ wt,
                                       int lane, int w, f4t (&acc)[NT][4])
{
  const int lm = lane & 15, lg = lane >> 4;
  #pragma unroll
  for (int step = 0; step < 10; ++step){
    bf8t a[4];
    #pragma unroll
    for (int rt = 0; rt < 4; ++rt)
      a[rt] = *(const bf8t*)(sm + abase + (unsigned)(rt*16 + lm)*656u + (unsigned)(step*32 + lg*8)*2u);
    #pragma unroll
    for (int t = 0; t < NT; ++t){
      int ct = w + t*8; if (ct > NCTM) ct = NCTM;
      bf8t bb = *(const bf8t*)(wt + (size_t)(ct*16 + lm)*320 + step*32 + lg*8);
      #pragma unroll
      for (int rt = 0; rt < 4; ++rt)
        acc[t][rt] = __builtin_amdgcn_mfma_f32_16x16x32_bf16(a[rt], bb, acc[t][rt], 0, 0, 0);
    }
  }
}

__device__ __forceinline__ void zero_acc(f4t (&acc)[3][4]){
  #pragma unroll
  for (int t = 0; t < 3; ++t)
    #pragma unroll
    for (int r = 0; r < 4; ++r) acc[t][r] = (f4t){0.f,0.f,0.f,0.f};
}

// pack C-frags (+bias) into bf16 pairs (rows i,i+1 share a u32)
__device__ __forceinline__ void packout(const f4t (&acc)[3][4],
    const float* __restrict__ b1, const float* __restrict__ b2,
    unsigned (&dst)[3][4][2], int w, int lm)
{
  #pragma unroll
  for (int t = 0; t < 3; ++t){
    int ct = w + t*8; if (ct > 18) ct = 18;
    int col = ct*16 + lm;
    float bb = (col < DD) ? (b2 ? (b1[col] + b2[col]) : b1[col]) : 0.f;
    #pragma unroll
    for (int r = 0; r < 4; ++r){
      dst[t][r][0] = packbf(acc[t][r][0]+bb, acc[t][r][1]+bb);
      dst[t][r][1] = packbf(acc[t][r][2]+bb, acc[t][r][3]+bb);
    }
  }
}

__global__ __launch_bounds__(512) void user_enc_kernel(
    const int*   __restrict__ ids, const float* __restrict__ uv,
    const float* __restrict__ emb,
    const float* __restrict__ bq, const float* __restrict__ bk,
    const float* __restrict__ bv, const float* __restrict__ bqp,
    const float* __restrict__ bkp,
    const float* __restrict__ ba, const float* __restrict__ qa,
    const short* __restrict__ wsb, float* __restrict__ out)
{
  __shared__ __align__(16) unsigned char sm[SM_TOTAL];
  const int tid  = threadIdx.x;
  const int b    = blockIdx.x;
  const int w    = tid >> 6;
  const int lane = tid & 63;
  const int lm   = lane & 15, lg = lane >> 4;
  const int l31  = lane & 31, hi = lane >> 5;

  const short* wqT  = wsb;
  const short* wkT  = wsb + WSEG;
  const short* wvT  = wsb + 2*WSEG;
  const short* wqpT = wsb + 3*WSEG;
  const short* wkpT = wsb + 4*WSEG;
  const short* waT  = wsb + WAOFF;

  // ---------------- phase 0: stage uv + gathered ue as bf16 (zero k-pad) -----
  if (tid < SS) *(int*)(sm + OFF_IDS + tid*4) = ids[(size_t)b*SS + tid];
  {
    const float* src = uv + (size_t)b*SS*DD;
    for (int i = tid; i < SS*160; i += 512){
      int s = i/160, j2 = i - s*160;
      unsigned val = 0;
      if (j2 < 150){ float2 v = *(const float2*)(src + s*DD + j2*2); val = packbf(v.x, v.y); }
      *(unsigned*)(sm + OFF_UV + (unsigned)s*656 + (unsigned)j2*4) = val;
    }
    // zero ctx pad cols 300..327 (bytes 600..655 per row)
    for (int i = tid; i < SS*14; i += 512)
      *(unsigned*)(sm + OFF_CTX + (unsigned)(i/14)*656 + 600u + (unsigned)(i%14)*4) = 0;
  }
  __syncthreads();
  for (int i = tid; i < SS*160; i += 512){
    int s = i/160, j2 = i - s*160;
    unsigned val = 0;
    if (j2 < 150){
      int id = *(const int*)(sm + OFF_IDS + s*4);
      float2 v = *(const float2*)(emb + (size_t)id*DD + j2*2);
      val = packbf(v.x, v.y);
    }
    *(unsigned*)(sm + OFF_UE + (unsigned)s*656 + (unsigned)j2*4) = val;
  }
  __syncthreads();

  // ---------------- phase 1: 5 MFMA projections -> packed bf16 registers -----
  unsigned pQc[3][4][2], pQp[3][4][2], pKs[3][4][2], pKc[3][4][2], pV[3][4][2];
  f4t acc[3][4];
  zero_acc(acc);
  gemm10<3,18>(sm, OFF_UV, wkT, lane, w, acc);
  packout(acc, bk, nullptr, pKc, w, lm);
  gemm10<3,18>(sm, OFF_UE, wkpT, lane, w, acc);   // continue same acc
  packout(acc, bk, bkp, pKs, w, lm);
  zero_acc(acc);
  gemm10<3,18>(sm, OFF_UV, wvT, lane, w, acc);
  packout(acc, bv, nullptr, pV, w, lm);
  zero_acc(acc);
  gemm10<3,18>(sm, OFF_UV, wqT, lane, w, acc);
  packout(acc, bq, nullptr, pQc, w, lm);
  zero_acc(acc);
  gemm10<3,18>(sm, OFF_UE, wqpT, lane, w, acc);
  packout(acc, bqp, nullptr, pQp, w, lm);

  // ---------------- phase 2: attention in 4 head-batches ----------------------
  const float rscale = 0.1290994449f;  // 1/sqrt(3*DK)
  #pragma unroll 1
  for (int nb = 0; nb < 4; ++nb){
    const int nheads = (nb < 3) ? 4 : 3;
    __syncthreads();   // prev batch reads done / staging dead
    // zero VT region (incl. key-pad cols and slack rows)
    for (int i = tid*16; i < VT_SZ; i += 512*16)
      *(float4*)(sm + OFF_VT + (unsigned)i) = make_float4(0.f,0.f,0.f,0.f);
    // zero Q/K per-head dim-pads (bytes 80..95 of each head slot)
    for (int i = tid; i < SS*4; i += 512){
      int r = i >> 2, hl0 = i & 3;
      *(float4*)(sm + OFF_Q + (unsigned)r*QKSTRIDE + (unsigned)hl0*96 + 80) = make_float4(0.f,0.f,0.f,0.f);
      *(float4*)(sm + OFF_K + (unsigned)r*QKSTRIDE + (unsigned)hl0*96 + 80) = make_float4(0.f,0.f,0.f,0.f);
    }
    // scatter this batch's columns from packed regs
    #pragma unroll
    for (int t = 0; t < 3; ++t){
      int ct = w + t*8; if (ct > 18) ct = 18;
      int col = ct*16 + lm;
      int head = col / 20;
      int dd = col - head*20;
      int hl0 = head - nb*4;
      if (hl0 >= 0 && hl0 < nheads){
        unsigned qb = OFF_Q + (unsigned)hl0*96 + (unsigned)dd*2;
        unsigned kb = OFF_K + (unsigned)hl0*96 + (unsigned)dd*2;
        unsigned vb = OFF_VT + (unsigned)(hl0*20 + dd)*144;
        #pragma unroll
        for (int rt2 = 0; rt2 < 4; ++rt2){
          int r0 = rt2*16 + lg*4;
          if (r0 < SS){
            *(unsigned*)(sm + vb + (unsigned)r0*2) = pV[t][rt2][0];
            if (r0 + 2 < SS) *(unsigned*)(sm + vb + (unsigned)r0*2 + 4) = pV[t][rt2][1];
            #pragma unroll
            for (int i = 0; i < 4; ++i){
              int row = r0 + i;
              if (row < SS){
                unsigned sh = 16u*(i&1);
                *(unsigned short*)(sm + qb + (unsigned)row*QKSTRIDE)      = (unsigned short)(pQc[t][rt2][i>>1] >> sh);
                *(unsigned short*)(sm + qb + 40 + (unsigned)row*QKSTRIDE) = (unsigned short)(pQp[t][rt2][i>>1] >> sh);
                *(unsigned short*)(sm + kb + (unsigned)row*QKSTRIDE)      = (unsigned short)(pKs[t][rt2][i>>1] >> sh);
                *(unsigned short*)(sm + kb + 40 + (unsigned)row*QKSTRIDE) = (unsigned short)(pKc[t][rt2][i>>1] >> sh);
              }
            }
          }
        }
      }
    }
    __syncthreads();   // layouts ready
    // ---- attention task: wave w -> head hl = w>>1, query-rowtile rt = w&1 ----
    const int ahl = w >> 1, rt = w & 1;
    if (ahl < nheads){
      // QK^T: 32x32 tiles, K=48 (3 steps of 16)
      f16t s0 = zero16(), s1 = zero16();
      unsigned aoff = OFF_Q + (unsigned)(rt*32 + l31)*QKSTRIDE + (unsigned)ahl*96 + (unsigned)hi*16;
      unsigned koff = OFF_K + (unsigned)l31*QKSTRIDE + (unsigned)ahl*96 + (unsigned)hi*16;
      #pragma unroll
      for (int ks = 0; ks < 3; ++ks){
        bf8t a  = *(const bf8t*)(sm + aoff + ks*32);
        bf8t b0 = *(const bf8t*)(sm + koff + ks*32);
        bf8t b1 = *(const bf8t*)(sm + koff + 32u*QKSTRIDE + ks*32);
        s0 = __builtin_amdgcn_mfma_f32_32x32x16_bf16(a, b0, s0, 0, 0, 0);
        s1 = __builtin_amdgcn_mfma_f32_32x32x16_bf16(a, b1, s1, 0, 0, 0);
      }
      // softmax per C-row; write unnormalized P (bf16); keep 1/sum per row
      const bool m1 = (l31 >= 18);   // key = 32+l31 >= 50
      unsigned pb = OFF_P + (unsigned)w*PBLK;
      float rinv[16];
      #pragma unroll
      for (int r = 0; r < 16; ++r){
        int lrow = (r&3) + 8*(r>>2) + 4*hi;
        float a0 = s0[r]*rscale;
        float a1 = m1 ? -INFINITY : s1[r]*rscale;
        float mx = fmaxf(a0, a1);
        #pragma unroll
        for (int off = 1; off <= 16; off <<= 1) mx = fmaxf(mx, __shfl_xor(mx, off));
        float e0 = __expf(a0 - mx);
        float e1 = m1 ? 0.f : __expf(a1 - mx);
        float sum = e0 + e1;
        #pragma unroll
        for (int off = 1; off <= 16; off <<= 1) sum += __shfl_xor(sum, off);
        rinv[r] = 1.0f / sum;
        *(unsigned short*)(sm + pb + (unsigned)lrow*144 + (unsigned)l31*2)      = f2bf(e0);
        *(unsigned short*)(sm + pb + (unsigned)lrow*144 + 64 + (unsigned)l31*2) = f2bf(e1);
      }
      // PV: P[32 q][64 k] @ V[64 k][d]; B from VT rows (ahl*20 + d)
      f16t c = zero16();
      unsigned pa  = pb + (unsigned)l31*144 + (unsigned)hi*16;
      unsigned vb2 = OFF_VT + (unsigned)(ahl*20 + l31)*144 + (unsigned)hi*16;
      #pragma unroll
      for (int ks = 0; ks < 4; ++ks){
        bf8t a = *(const bf8t*)(sm + pa + ks*32);
        bf8t v = *(const bf8t*)(sm + vb2 + ks*32);
        c = __builtin_amdgcn_mfma_f32_32x32x16_bf16(a, v, c, 0, 0, 0);
      }
      // ctx write (normalize here)
      if (l31 < HD){
        int h = nb*4 + ahl;
        #pragma unroll
        for (int r = 0; r < 16; ++r){
          int q = rt*32 + (r&3) + 8*(r>>2) + 4*hi;
          if (q < SS)
            *(unsigned short*)(sm + OFF_CTX + (unsigned)q*656 + (unsigned)(h*HD + l31)*2) =
                f2bf(c[r]*rinv[r]);
        }
      }
    }
  }
  __syncthreads();   // ctx complete

  // ---------------- phase 3: additive pooling --------------------------------
  {
    f4t accp[2][4];
    #pragma unroll
    for (int t = 0; t < 2; ++t)
      #pragma unroll
      for (int r = 0; r < 4; ++r) accp[t][r] = (f4t){0.f,0.f,0.f,0.f};
    gemm10<2,12>(sm, OFF_CTX, waT, lane, w, accp);
    float part[4][4];
    #pragma unroll
    for (int rt2 = 0; rt2 < 4; ++rt2)
      #pragma unroll
      for (int i = 0; i < 4; ++i) part[rt2][i] = 0.f;
    #pragma unroll
    for (int t = 0; t < 2; ++t){
      int ct = w + t*8; if (ct > 12) ct = 12;
      bool valid = (t == 0) || (w < 5);
      int col = ct*16 + lm;
      float bav = (col < QDIM) ? ba[col] : 0.f;
      float qav = (valid && col < QDIM) ? qa[col] : 0.f;
      #pragma unroll
      for (int rt2 = 0; rt2 < 4; ++rt2)
        #pragma unroll
        for (int i = 0; i < 4; ++i)
          part[rt2][i] += tanhf(accp[t][rt2][i] + bav) * qav;
    }
    #pragma unroll
    for (int off = 1; off <= 8; off <<= 1)
      #pragma unroll
      for (int rt2 = 0; rt2 < 4; ++rt2)
        #pragma unroll
        for (int i = 0; i < 4; ++i)
          part[rt2][i] += __shfl_xor(part[rt2][i], off);
    if (lm == 0){
      #pragma unroll
      for (int rt2 = 0; rt2 < 4; ++rt2)
        #pragma unroll
        for (int i = 0; i < 4; ++i){
          int row = rt2*16 + lg*4 + i;
          if (row < SS) *(float*)(sm + OFF_LG + (unsigned)(row*8 + w)*4) = part[rt2][i];
        }
    }
  }
  __syncthreads();
  if (w == 0){
    const int sl = lane < SS ? lane : SS - 1;
    const bool rowok = lane < SS;
    float lgv = -INFINITY;
    if (rowok){
      float s = 0.f;
      #pragma unroll
      for (int j = 0; j < 8; ++j) s += *(const float*)(sm + OFF_LG + (unsigned)(sl*8 + j)*4);
      lgv = s;
    }
    float m = lgv;
    #pragma unroll
    for (int off = 32; off; off >>= 1) m = fmaxf(m, __shfl_xor(m, off));
    float e = rowok ? __expf(lgv - m) : 0.f;
    float ssum = e;
    #pragma unroll
    for (int off = 32; off; off >>= 1) ssum += __shfl_xor(ssum, off);
    *(float*)(sm + OFF_A2 + lane*4) = e / ssum;
  }
  __syncthreads();
  // ---------------- phase 4: output ------------------------------------------
  if (tid < DD){
    float accv = 0.f;
    for (int s = 0; s < SS; ++s){
      float av = *(const float*)(sm + OFF_A2 + (unsigned)s*4);
      unsigned short cv = *(const unsigned short*)(sm + OFF_CTX + (unsigned)s*656 + (unsigned)tid*2);
      accv = fmaf(av, __uint_as_float((unsigned)cv << 16), accv);
    }
    out[(size_t)b*DD + tid] = accv;
  }
}

extern "C" void kernel_launch(void* const* d_in, const int* in_sizes, int n_in,
                              void* d_out, int out_size, void* d_ws, size_t ws_size,
                              hipStream_t stream){
  (void)n_in; (void)ws_size; (void)out_size;
  const int*   ids = (const int*)  d_in[0];
  const float* uvp = (const float*)d_in[1];
  const float* emb = (const float*)d_in[2];
  const float* Wq  = (const float*)d_in[3];
  const float* bq  = (const float*)d_in[4];
  const float* Wk  = (const float*)d_in[5];
  const float* bk  = (const float*)d_in[6];
  const float* Wv  = (const float*)d_in[7];
  const float* bv  = (const float*)d_in[8];
  const float* Wqp = (const float*)d_in[9];
  const float* bqp = (const float*)d_in[10];
  const float* Wkp = (const float*)d_in[11];
  const float* bkp = (const float*)d_in[12];
  const float* Wa  = (const float*)d_in[13];
  const float* ba  = (const float*)d_in[14];
  const float* qa  = (const float*)d_in[15];
  short* wsb = (short*)d_ws;

  conv_weights<<<(WTOT + 255)/256, 256, 0, stream>>>(Wq, Wk, Wv, Wqp, Wkp, Wa, wsb);

  const int nb = in_sizes[0] / SS;   // 1024
  user_enc_kernel<<<nb, 512, 0, stream>>>(ids, uvp, emb,
                                          bq, bk, bv, bqp, bkp, ba, qa,
                                          (const short*)wsb, (float*)d_out);
}

// Round 4
// 419.267 us; speedup vs baseline: 9.8849x; 1.2431x over previous
//
#include <hip/hip_runtime.h>
#include <hip/hip_bf16.h>

#define SS   50     // sequence length
#define DD   300    // embedding dim
#define NH   15     // heads
#define HD   20     // per-head dim
#define QDIM 200    // additive attention dim

// ---------------- LDS layout (bytes) ----------------
// uv/ue bf16 [50][328] stride 656 (k-pad zeroed), live for whole kernel.
// Per head-batch (<=4 heads):
//   Q [50][4h x 48d] stride 400 @ OFF_Q ([Qc20|Qp20|8zero] per head)
//   K same @ OFF_K ([Ksum20|Kc20|8zero])
//   VT [80 dims][64 keys] stride 144 @ OFF_VT (zeroed once; keys>=50 stay 0)
//   P (overlays Q+K after QK^T): per-wave [32][64k] stride 144 @ OFF_P + w*4608
// ctx bf16 [50][328] stride 656 @ OFF_CTX (persists; k-pad zeroed)
// pooling: lg2d f32 [50][8] @ OFF_LG; a f32[64] @ OFF_A2; ids @ OFF_IDS
#define OFF_UV  0
#define OFF_UE  32800
#define QKSTR   400
#define OFF_Q   65600
#define OFF_K   85600
#define OFF_P   65600
#define PBLK    4608
#define PSTR    144
#define VTSTR   144
#define OFF_VT  105600
#define OFF_CTX 117120
#define OFF_LG  159104
#define OFF_A2  161152
#define OFF_IDS 161408
#define SM_TOTAL 161616

// ws (bf16 elements): 5 proj [304][320] + Wa [208][320]
#define WSEG  97280
#define WAOFF 486400
#define WTOT  552960

typedef __attribute__((ext_vector_type(8)))  short bf8t;
typedef __attribute__((ext_vector_type(4)))  float f4t;
typedef __attribute__((ext_vector_type(16))) float f16t;

__device__ __forceinline__ unsigned short f2bf(float x){
  unsigned u = __float_as_uint(x);
  return (unsigned short)((u + 0x7fffu + ((u >> 16) & 1u)) >> 16);
}
__device__ __forceinline__ unsigned packbf(float a, float b){
  return (unsigned)f2bf(a) | ((unsigned)f2bf(b) << 16);
}
__device__ __forceinline__ f16t zero16(){
  f16t v;
  #pragma unroll
  for (int i = 0; i < 16; ++i) v[i] = 0.f;
  return v;
}

// ---------------- weight converter: f32 [300][N] -> bf16 [Npad][320] (B^T, zero-padded)
__global__ __launch_bounds__(256) void conv_weights(
    const float* __restrict__ Wq, const float* __restrict__ Wk,
    const float* __restrict__ Wv, const float* __restrict__ Wqp,
    const float* __restrict__ Wkp, const float* __restrict__ Wa,
    short* __restrict__ ws)
{
  int idx = blockIdx.x*256 + threadIdx.x;
  if (idx >= WTOT) return;
  float v = 0.f;
  if (idx < WAOFF){
    int seg = idx / WSEG, r = idx - seg*WSEG;
    int n = r / 320, k = r - n*320;
    const float* W = (seg==0)?Wq:(seg==1)?Wk:(seg==2)?Wv:(seg==3)?Wqp:Wkp;
    if (n < DD && k < DD) v = W[k*DD + n];
  } else {
    int r = idx - WAOFF;
    int n = r / 320, k = r - n*320;
    if (n < QDIM && k < DD) v = Wa[k*QDIM + n];
  }
  ws[idx] = (short)f2bf(v);
}

// ---------------- pooling GEMM helper (as r3): acc += A(LDS) @ B(ws), 10 k-steps
template<int NT, int NCTM>
__device__ __forceinline__ void gemm10(const unsigned char* sm, unsigned abase,
                                       const short* __restrict__ wt,
                                       int lane, int w, f4t (&acc)[NT][4])
{
  const int lm = lane & 15, lg = lane >> 4;
  #pragma unroll
  for (int step = 0; step < 10; ++step){
    bf8t a[4];
    #pragma unroll
    for (int rt = 0; rt < 4; ++rt)
      a[rt] = *(const bf8t*)(sm + abase + (unsigned)(rt*16 + lm)*656u + (unsigned)(step*32 + lg*8)*2u);
    #pragma unroll
    for (int t = 0; t < NT; ++t){
      int ct = w + t*8; if (ct > NCTM) ct = NCTM;
      bf8t bb = *(const bf8t*)(wt + (size_t)(ct*16 + lm)*320 + step*32 + lg*8);
      #pragma unroll
      for (int rt = 0; rt < 4; ++rt)
        acc[t][rt] = __builtin_amdgcn_mfma_f32_16x16x32_bf16(a[rt], bb, acc[t][rt], 0, 0, 0);
    }
  }
}

__global__ __launch_bounds__(512) void user_enc_kernel(
    const int*   __restrict__ ids, const float* __restrict__ uv,
    const float* __restrict__ emb,
    const float* __restrict__ bq, const float* __restrict__ bk,
    const float* __restrict__ bv, const float* __restrict__ bqp,
    const float* __restrict__ bkp,
    const float* __restrict__ ba, const float* __restrict__ qa,
    const short* __restrict__ wsb, float* __restrict__ out)
{
  __shared__ __align__(16) unsigned char sm[SM_TOTAL];
  const int tid  = threadIdx.x;
  const int b    = blockIdx.x;
  const int w    = tid >> 6;
  const int lane = tid & 63;
  const int lm   = lane & 15, lg = lane >> 4;
  const int l31  = lane & 31, hi = lane >> 5;

  const short* wqT  = wsb;
  const short* wkT  = wsb + WSEG;
  const short* wvT  = wsb + 2*WSEG;
  const short* wqpT = wsb + 3*WSEG;
  const short* wkpT = wsb + 4*WSEG;
  const short* waT  = wsb + WAOFF;

  // ---------------- phase 0: stage uv (bf16) + zero pads/VT -------------------
  if (tid < SS) *(int*)(sm + OFF_IDS + tid*4) = ids[(size_t)b*SS + tid];
  {
    const float* srcv = uv + (size_t)b*SS*DD;
    for (int i = tid; i < SS*75; i += 512){
      int s = i/75, j4 = i - s*75;
      float4 v = *(const float4*)(srcv + s*DD + j4*4);
      *(unsigned*)(sm + OFF_UV + (unsigned)s*656 + (unsigned)j4*8)     = packbf(v.x, v.y);
      *(unsigned*)(sm + OFF_UV + (unsigned)s*656 + (unsigned)j4*8 + 4) = packbf(v.z, v.w);
    }
    for (int i = tid; i < SS*28; i += 512){   // uv+ue k-pads (cols 300..327)
      int s = i/28, j = i - s*28;
      unsigned off = (j < 14) ? (OFF_UV + (unsigned)s*656 + 600u + (unsigned)j*4)
                              : (OFF_UE + (unsigned)s*656 + 600u + (unsigned)(j-14)*4);
      *(unsigned*)(sm + off) = 0;
    }
    for (int i = tid; i < SS*14; i += 512)    // ctx k-pads
      *(unsigned*)(sm + OFF_CTX + (unsigned)(i/14)*656 + 600u + (unsigned)(i%14)*4) = 0;
    for (int i = tid; i < 720; i += 512)      // VT (zeros persist at keys>=50)
      *(float4*)(sm + OFF_VT + (unsigned)i*16) = make_float4(0.f,0.f,0.f,0.f);
  }
  __syncthreads();
  for (int i = tid; i < SS*75; i += 512){     // gather ue
    int s = i/75, j4 = i - s*75;
    int id = *(const int*)(sm + OFF_IDS + s*4);
    float4 v = *(const float4*)(emb + (size_t)id*DD + j4*4);
    *(unsigned*)(sm + OFF_UE + (unsigned)s*656 + (unsigned)j4*8)     = packbf(v.x, v.y);
    *(unsigned*)(sm + OFF_UE + (unsigned)s*656 + (unsigned)j4*8 + 4) = packbf(v.z, v.w);
  }

  // ---------------- fused projection + attention, 4 head-batches --------------
  const float rscale = 0.1290994449f;  // 1/sqrt(3*DK)
  #pragma unroll 1
  for (int nb4 = 0; nb4 < 4; ++nb4){
    const int nheads = (nb4 < 3) ? 4 : 3;
    const int NCT    = (nb4 < 3) ? 5 : 4;
    __syncthreads();   // prev batch P/VT reads done; batch 0: staging/zeros done
    // re-zero Q/K per-head dim pads (bytes 80..95 of each 96B slot) — P killed them
    for (int i = tid; i < SS*4; i += 512){
      int r = i >> 2, hl0 = i & 3;
      *(float4*)(sm + OFF_Q + (unsigned)r*QKSTR + (unsigned)hl0*96 + 80) = make_float4(0.f,0.f,0.f,0.f);
      *(float4*)(sm + OFF_K + (unsigned)r*QKSTR + (unsigned)hl0*96 + 80) = make_float4(0.f,0.f,0.f,0.f);
    }
    // projection half-tasks: this batch's 80 output cols for Qc,Qp,V,K(->Kc,Ksum)
    // (scatter targets are dim bytes 0..79 per slot — disjoint from pad zeroing)
    for (int ht = w; ht < 8*NCT; ht += 8){
      const int g   = (ht >= 6*NCT) ? 3 : (ht >= 4*NCT) ? 2 : (ht >= 2*NCT) ? 1 : 0;
      const int rem = ht - g*2*NCT;
      const int c   = rem >> 1, rh = rem & 1;
      const int col = nb4*80 + c*16 + lm;
      const int colc = (col < DD) ? col : DD-1;
      const int head = col / HD;
      const int dd   = col - head*HD;
      const int hl   = head - nb4*4;
      const bool valid = (hl < nheads) && (col < DD);
      const unsigned abase = (g == 1) ? (unsigned)OFF_UE : (unsigned)OFF_UV;
      const short* wt = (g==0) ? wqT : (g==1) ? wqpT : (g==2) ? wvT : wkT;
      const short* wb = wt + (size_t)col*320 + lg*8;
      f4t a0 = {0.f,0.f,0.f,0.f}, a1 = {0.f,0.f,0.f,0.f};
      #pragma unroll
      for (int st = 0; st < 10; ++st){
        bf8t bb = *(const bf8t*)(wb + st*32);
        bf8t x0 = *(const bf8t*)(sm + abase + (unsigned)(rh*32 + lm)*656u + (unsigned)(st*32 + lg*8)*2u);
        bf8t x1 = *(const bf8t*)(sm + abase + (unsigned)(rh*32 + 16 + lm)*656u + (unsigned)(st*32 + lg*8)*2u);
        a0 = __builtin_amdgcn_mfma_f32_16x16x32_bf16(x0, bb, a0, 0, 0, 0);
        a1 = __builtin_amdgcn_mfma_f32_16x16x32_bf16(x1, bb, a1, 0, 0, 0);
      }
      if (g == 2){
        if (valid){
          float bias = bv[colc];
          unsigned vb = OFF_VT + (unsigned)(hl*HD + dd)*VTSTR;
          int r0 = rh*32 + lg*4;
          if (r0 < SS){
            *(unsigned*)(sm + vb + (unsigned)r0*2) = packbf(a0[0]+bias, a0[1]+bias);
            if (r0+2 < SS) *(unsigned*)(sm + vb + (unsigned)r0*2 + 4) = packbf(a0[2]+bias, a0[3]+bias);
          }
          int r1 = rh*32 + 16 + lg*4;
          if (r1 < SS){
            *(unsigned*)(sm + vb + (unsigned)r1*2) = packbf(a1[0]+bias, a1[1]+bias);
            if (r1+2 < SS) *(unsigned*)(sm + vb + (unsigned)r1*2 + 4) = packbf(a1[2]+bias, a1[3]+bias);
          }
        }
      } else if (g != 3){
        if (valid){
          float bias = (g==0) ? bq[colc] : bqp[colc];
          unsigned qb = OFF_Q + (unsigned)hl*96 + (unsigned)dd*2 + (g==1 ? 40u : 0u);
          #pragma unroll
          for (int i = 0; i < 4; ++i){
            int r0 = rh*32 + lg*4 + i;
            if (r0 < SS) *(unsigned short*)(sm + qb + (unsigned)r0*QKSTR) = f2bf(a0[i]+bias);
            int r1 = rh*32 + 16 + lg*4 + i;
            if (r1 < SS) *(unsigned short*)(sm + qb + (unsigned)r1*QKSTR) = f2bf(a1[i]+bias);
          }
        }
      } else {
        // K task: Kc = uv@Wk + bk, then continue acc with ue@Wkp -> Ksum
        float bkc = bk[colc];
        if (valid){
          unsigned kb = OFF_K + (unsigned)hl*96 + (unsigned)dd*2 + 40u;  // Kc slot
          #pragma unroll
          for (int i = 0; i < 4; ++i){
            int r0 = rh*32 + lg*4 + i;
            if (r0 < SS) *(unsigned short*)(sm + kb + (unsigned)r0*QKSTR) = f2bf(a0[i]+bkc);
            int r1 = rh*32 + 16 + lg*4 + i;
            if (r1 < SS) *(unsigned short*)(sm + kb + (unsigned)r1*QKSTR) = f2bf(a1[i]+bkc);
          }
        }
        const short* wb2 = wkpT + (size_t)col*320 + lg*8;
        #pragma unroll
        for (int st = 0; st < 10; ++st){
          bf8t bb = *(const bf8t*)(wb2 + st*32);
          bf8t x0 = *(const bf8t*)(sm + OFF_UE + (unsigned)(rh*32 + lm)*656u + (unsigned)(st*32 + lg*8)*2u);
          bf8t x1 = *(const bf8t*)(sm + OFF_UE + (unsigned)(rh*32 + 16 + lm)*656u + (unsigned)(st*32 + lg*8)*2u);
          a0 = __builtin_amdgcn_mfma_f32_16x16x32_bf16(x0, bb, a0, 0, 0, 0);
          a1 = __builtin_amdgcn_mfma_f32_16x16x32_bf16(x1, bb, a1, 0, 0, 0);
        }
        if (valid){
          float bsum = bkc + bkp[colc];
          unsigned kb = OFF_K + (unsigned)hl*96 + (unsigned)dd*2;        // Ksum slot
          #pragma unroll
          for (int i = 0; i < 4; ++i){
            int r0 = rh*32 + lg*4 + i;
            if (r0 < SS) *(unsigned short*)(sm + kb + (unsigned)r0*QKSTR) = f2bf(a0[i]+bsum);
            int r1 = rh*32 + 16 + lg*4 + i;
            if (r1 < SS) *(unsigned short*)(sm + kb + (unsigned)r1*QKSTR) = f2bf(a1[i]+bsum);
          }
        }
      }
    }
    __syncthreads();   // Q/K/VT layouts ready
    // ---- attention: wave -> (head hl = w>>1, query tile rt = w&1) ----
    const int ahl = w >> 1, rt = w & 1;
    const bool act = (ahl < nheads);
    f16t s0, s1;
    if (act){
      s0 = zero16(); s1 = zero16();
      unsigned aoff = OFF_Q + (unsigned)(rt*32 + l31)*QKSTR + (unsigned)ahl*96 + (unsigned)hi*16;
      unsigned koff = OFF_K + (unsigned)l31*QKSTR + (unsigned)ahl*96 + (unsigned)hi*16;
      #pragma unroll
      for (int ks = 0; ks < 3; ++ks){
        bf8t a  = *(const bf8t*)(sm + aoff + ks*32);
        bf8t b0 = *(const bf8t*)(sm + koff + ks*32);
        bf8t b1 = *(const bf8t*)(sm + koff + 32u*QKSTR + ks*32);
        s0 = __builtin_amdgcn_mfma_f32_32x32x16_bf16(a, b0, s0, 0, 0, 0);
        s1 = __builtin_amdgcn_mfma_f32_32x32x16_bf16(a, b1, s1, 0, 0, 0);
      }
    }
    __syncthreads();   // all Q/K reads done -> P may overwrite region
    if (act){
      const bool m1 = (l31 >= 18);   // key 32+l31 >= 50
      unsigned pb = OFF_P + (unsigned)w*PBLK;
      float rinv[16];
      #pragma unroll
      for (int r = 0; r < 16; ++r){
        int lrow = (r&3) + 8*(r>>2) + 4*hi;
        float v0 = s0[r]*rscale;
        float v1 = m1 ? -INFINITY : s1[r]*rscale;
        float mx = fmaxf(v0, v1);
        #pragma unroll
        for (int off = 1; off <= 16; off <<= 1) mx = fmaxf(mx, __shfl_xor(mx, off));
        float e0 = __expf(v0 - mx);
        float e1 = m1 ? 0.f : __expf(v1 - mx);
        float sum = e0 + e1;
        #pragma unroll
        for (int off = 1; off <= 16; off <<= 1) sum += __shfl_xor(sum, off);
        rinv[r] = 1.0f/sum;
        *(unsigned short*)(sm + pb + (unsigned)lrow*PSTR + (unsigned)l31*2)      = f2bf(e0);
        *(unsigned short*)(sm + pb + (unsigned)lrow*PSTR + 64 + (unsigned)l31*2) = f2bf(e1);
      }
      // PV: own P block (within-wave RAW handled by compiler waitcnt)
      f16t c = zero16();
      unsigned pa  = pb + (unsigned)l31*PSTR + (unsigned)hi*16;
      unsigned vb2 = OFF_VT + (unsigned)(ahl*HD + l31)*VTSTR + (unsigned)hi*16;
      #pragma unroll
      for (int ks = 0; ks < 4; ++ks){
        bf8t a = *(const bf8t*)(sm + pa + ks*32);
        bf8t v = *(const bf8t*)(sm + vb2 + ks*32);
        c = __builtin_amdgcn_mfma_f32_32x32x16_bf16(a, v, c, 0, 0, 0);
      }
      if (l31 < HD){
        int h = nb4*4 + ahl;
        #pragma unroll
        for (int r = 0; r < 16; ++r){
          int q = rt*32 + (r&3) + 8*(r>>2) + 4*hi;
          if (q < SS)
            *(unsigned short*)(sm + OFF_CTX + (unsigned)q*656 + (unsigned)(h*HD + l31)*2) =
                f2bf(c[r]*rinv[r]);
        }
      }
    }
  }
  __syncthreads();   // ctx complete

  // ---------------- pooling --------------------------------------------------
  {
    f4t accp[2][4];
    #pragma unroll
    for (int t = 0; t < 2; ++t)
      #pragma unroll
      for (int r = 0; r < 4; ++r) accp[t][r] = (f4t){0.f,0.f,0.f,0.f};
    gemm10<2,12>(sm, OFF_CTX, waT, lane, w, accp);
    float part[4][4];
    #pragma unroll
    for (int rt2 = 0; rt2 < 4; ++rt2)
      #pragma unroll
      for (int i = 0; i < 4; ++i) part[rt2][i] = 0.f;
    #pragma unroll
    for (int t = 0; t < 2; ++t){
      int ct = w + t*8; if (ct > 12) ct = 12;
      bool valid = (t == 0) || (w < 5);
      int col = ct*16 + lm;
      float bav = (col < QDIM) ? ba[col] : 0.f;
      float qav = (valid && col < QDIM) ? qa[col] : 0.f;
      #pragma unroll
      for (int rt2 = 0; rt2 < 4; ++rt2)
        #pragma unroll
        for (int i = 0; i < 4; ++i)
          part[rt2][i] += tanhf(accp[t][rt2][i] + bav) * qav;
    }
    #pragma unroll
    for (int off = 1; off <= 8; off <<= 1)
      #pragma unroll
      for (int rt2 = 0; rt2 < 4; ++rt2)
        #pragma unroll
        for (int i = 0; i < 4; ++i)
          part[rt2][i] += __shfl_xor(part[rt2][i], off);
    if (lm == 0){
      #pragma unroll
      for (int rt2 = 0; rt2 < 4; ++rt2)
        #pragma unroll
        for (int i = 0; i < 4; ++i){
          int row = rt2*16 + lg*4 + i;
          if (row < SS) *(float*)(sm + OFF_LG + (unsigned)(row*8 + w)*4) = part[rt2][i];
        }
    }
  }
  __syncthreads();
  if (w == 0){
    const int sl = lane < SS ? lane : SS - 1;
    const bool rowok = lane < SS;
    float lgv = -INFINITY;
    if (rowok){
      float s = 0.f;
      #pragma unroll
      for (int j = 0; j < 8; ++j) s += *(const float*)(sm + OFF_LG + (unsigned)(sl*8 + j)*4);
      lgv = s;
    }
    float m = lgv;
    #pragma unroll
    for (int off = 32; off; off >>= 1) m = fmaxf(m, __shfl_xor(m, off));
    float e = rowok ? __expf(lgv - m) : 0.f;
    float ssum = e;
    #pragma unroll
    for (int off = 32; off; off >>= 1) ssum += __shfl_xor(ssum, off);
    *(float*)(sm + OFF_A2 + lane*4) = e / ssum;
  }
  __syncthreads();
  // ---------------- output ----------------------------------------------------
  if (tid < DD){
    float accv = 0.f;
    for (int s = 0; s < SS; ++s){
      float av = *(const float*)(sm + OFF_A2 + (unsigned)s*4);
      unsigned short cv = *(const unsigned short*)(sm + OFF_CTX + (unsigned)s*656 + (unsigned)tid*2);
      accv = fmaf(av, __uint_as_float((unsigned)cv << 16), accv);
    }
    out[(size_t)b*DD + tid] = accv;
  }
}

extern "C" void kernel_launch(void* const* d_in, const int* in_sizes, int n_in,
                              void* d_out, int out_size, void* d_ws, size_t ws_size,
                              hipStream_t stream){
  (void)n_in; (void)ws_size; (void)out_size;
  const int*   ids = (const int*)  d_in[0];
  const float* uvp = (const float*)d_in[1];
  const float* emb = (const float*)d_in[2];
  const float* Wq  = (const float*)d_in[3];
  const float* bq  = (const float*)d_in[4];
  const float* Wk  = (const float*)d_in[5];
  const float* bk  = (const float*)d_in[6];
  const float* Wv  = (const float*)d_in[7];
  const float* bv  = (const float*)d_in[8];
  const float* Wqp = (const float*)d_in[9];
  const float* bqp = (const float*)d_in[10];
  const float* Wkp = (const float*)d_in[11];
  const float* bkp = (const float*)d_in[12];
  const float* Wa  = (const float*)d_in[13];
  const float* ba  = (const float*)d_in[14];
  const float* qa  = (const float*)d_in[15];
  short* wsb = (short*)d_ws;

  conv_weights<<<(WTOT + 255)/256, 256, 0, stream>>>(Wq, Wk, Wv, Wqp, Wkp, Wa, wsb);

  const int nblk = in_sizes[0] / SS;   // 1024
  user_enc_kernel<<<nblk, 512, 0, stream>>>(ids, uvp, emb,
                                            bq, bk, bv, bqp, bkp, ba, qa,
                                            (const short*)wsb, (float*)d_out);
}

// Round 6
// 397.880 us; speedup vs baseline: 10.4162x; 1.0538x over previous
//
#include <hip/hip_runtime.h>
#include <hip/hip_bf16.h>

#define SS   50     // sequence length
#define DD   300    // embedding dim
#define NH   15     // heads
#define HD   20     // per-head dim
#define QDIM 200    // additive attention dim

// ws (bf16 elements): 5 proj [304][320] + Wa [208][320]
#define WSEG  97280
#define WAOFF 486400
#define WTOT  552960

typedef __attribute__((ext_vector_type(8)))  short bf8t;
typedef __attribute__((ext_vector_type(4)))  float f4t;
typedef __attribute__((ext_vector_type(16))) float f16t;

__device__ __forceinline__ unsigned short f2bf(float x){
  unsigned u = __float_as_uint(x);
  return (unsigned short)((u + 0x7fffu + ((u >> 16) & 1u)) >> 16);
}
__device__ __forceinline__ unsigned packbf(float a, float b){
  return (unsigned)f2bf(a) | ((unsigned)f2bf(b) << 16);
}
__device__ __forceinline__ f16t zero16(){
  f16t v;
  #pragma unroll
  for (int i = 0; i < 16; ++i) v[i] = 0.f;
  return v;
}

// ---------------- weight converter: f32 [300][N] -> bf16 [Npad][320] (B^T, zero-padded)
__global__ __launch_bounds__(256) void conv_weights(
    const float* __restrict__ Wq, const float* __restrict__ Wk,
    const float* __restrict__ Wv, const float* __restrict__ Wqp,
    const float* __restrict__ Wkp, const float* __restrict__ Wa,
    short* __restrict__ ws)
{
  int idx = blockIdx.x*256 + threadIdx.x;
  if (idx >= WTOT) return;
  float v = 0.f;
  if (idx < WAOFF){
    int seg = idx / WSEG, r = idx - seg*WSEG;
    int n = r / 320, k = r - n*320;
    const float* W = (seg==0)?Wq:(seg==1)?Wk:(seg==2)?Wv:(seg==3)?Wqp:Wkp;
    if (n < DD && k < DD) v = W[k*DD + n];
  } else {
    int r = idx - WAOFF;
    int n = r / 320, k = r - n*320;
    if (n < QDIM && k < DD) v = Wa[k*QDIM + n];
  }
  ws[idx] = (short)f2bf(v);
}

// ---------------- pooling GEMM helper: acc += A(LDS,stride656) @ B(ws), 10 k-steps
template<int NT, int NCTM>
__device__ __forceinline__ void gemm10(const unsigned char* sm, unsigned abase,
                                       const short* __restrict__ wt,
                                       int lane, int w, f4t (&acc)[NT][4])
{
  const int lm = lane & 15, lg = lane >> 4;
  #pragma unroll
  for (int step = 0; step < 10; ++step){
    bf8t a[4];
    #pragma unroll
    for (int rt = 0; rt < 4; ++rt)
      a[rt] = *(const bf8t*)(sm + abase + (unsigned)(rt*16 + lm)*656u + (unsigned)(step*32 + lg*8)*2u);
    #pragma unroll
    for (int t = 0; t < NT; ++t){
      int ct = w + t*8; if (ct > NCTM) ct = NCTM;
      bf8t bb = *(const bf8t*)(wt + (size_t)(ct*16 + lm)*320 + step*32 + lg*8);
      #pragma unroll
      for (int rt = 0; rt < 4; ++rt)
        acc[t][rt] = __builtin_amdgcn_mfma_f32_16x16x32_bf16(a[rt], bb, acc[t][rt], 0, 0, 0);
    }
  }
}

// ============================ K1: projections ================================
// LDS: uv [50][328]bf16 stride656 @0; ue @32800; (overread pad to 64 rows); ids @74784
#define K1_UV  0
#define K1_UE  32800
#define K1_IDS 74784
#define K1_SM  74992

__global__ __launch_bounds__(512) void k1_proj(
    const int*   __restrict__ ids, const float* __restrict__ uv,
    const float* __restrict__ emb,
    const float* __restrict__ bq, const float* __restrict__ bk,
    const float* __restrict__ bv, const float* __restrict__ bqp,
    const float* __restrict__ bkp,
    const short* __restrict__ wsb,
    short* __restrict__ qg, short* __restrict__ kg, short* __restrict__ vg)
{
  __shared__ __align__(16) unsigned char sm[K1_SM];
  const int tid  = threadIdx.x;
  const int b    = blockIdx.x;
  const int w    = tid >> 6;
  const int lane = tid & 63;
  const int lm   = lane & 15, lg = lane >> 4;

  const short* wqT  = wsb;
  const short* wkT  = wsb + WSEG;
  const short* wvT  = wsb + 2*WSEG;
  const short* wqpT = wsb + 3*WSEG;
  const short* wkpT = wsb + 4*WSEG;

  if (tid < SS) *(int*)(sm + K1_IDS + tid*4) = ids[(size_t)b*SS + tid];
  {
    const float* srcv = uv + (size_t)b*SS*DD;
    for (int i = tid; i < SS*75; i += 512){
      int s = i/75, j4 = i - s*75;
      float4 v = *(const float4*)(srcv + s*DD + j4*4);
      *(unsigned*)(sm + K1_UV + (unsigned)s*656 + (unsigned)j4*8)     = packbf(v.x, v.y);
      *(unsigned*)(sm + K1_UV + (unsigned)s*656 + (unsigned)j4*8 + 4) = packbf(v.z, v.w);
    }
    for (int i = tid; i < SS*28; i += 512){   // uv+ue k-pads (cols 300..327)
      int s = i/28, j = i - s*28;
      unsigned off = (j < 14) ? (K1_UV + (unsigned)s*656 + 600u + (unsigned)j*4)
                              : (K1_UE + (unsigned)s*656 + 600u + (unsigned)(j-14)*4);
      *(unsigned*)(sm + off) = 0;
    }
  }
  __syncthreads();
  for (int i = tid; i < SS*75; i += 512){     // gather ue
    int s = i/75, j4 = i - s*75;
    int id = *(const int*)(sm + K1_IDS + s*4);
    float4 v = *(const float4*)(emb + (size_t)id*DD + j4*4);
    *(unsigned*)(sm + K1_UE + (unsigned)s*656 + (unsigned)j4*8)     = packbf(v.x, v.y);
    *(unsigned*)(sm + K1_UE + (unsigned)s*656 + (unsigned)j4*8 + 4) = packbf(v.z, v.w);
  }
  __syncthreads();

  // zero 48-dim pads (cols head*48 + 40..47) of qg/kg rows of this b
  for (int i = tid; i < SS*15*4; i += 512){
    int row = i / 60, r2 = i - row*60;
    int head = r2 >> 2, j = r2 & 3;
    size_t base = ((size_t)b*SS + row)*720 + head*48 + 40 + j*2;
    *(unsigned*)(qg + base) = 0u;
    *(unsigned*)(kg + base) = 0u;
  }

  // 152 task-units: g in {Qc,Qp,V,K}, 19 col-tiles, 2 row-halves
  for (int u = w; u < 152; u += 8){
    const int g   = u / 38;
    const int rem = u - g*38;
    const int c   = rem >> 1, rh = rem & 1;
    const int col  = c*16 + lm;
    const int colc = (col < DD) ? col : DD-1;
    const bool valid = (col < DD);
    const int head = colc / HD;
    const int dd   = colc - head*HD;
    const unsigned abase = (g == 1) ? (unsigned)K1_UE : (unsigned)K1_UV;
    const short* wt = (g==0) ? wqT : (g==1) ? wqpT : (g==2) ? wvT : wkT;
    const short* wb = wt + (size_t)col*320 + lg*8;
    f4t a0 = {0.f,0.f,0.f,0.f}, a1 = {0.f,0.f,0.f,0.f};
    #pragma unroll
    for (int st = 0; st < 10; ++st){
      bf8t bb = *(const bf8t*)(wb + st*32);
      bf8t x0 = *(const bf8t*)(sm + abase + (unsigned)(rh*32 + lm)*656u + (unsigned)(st*32 + lg*8)*2u);
      bf8t x1 = *(const bf8t*)(sm + abase + (unsigned)(rh*32 + 16 + lm)*656u + (unsigned)(st*32 + lg*8)*2u);
      a0 = __builtin_amdgcn_mfma_f32_16x16x32_bf16(x0, bb, a0, 0, 0, 0);
      a1 = __builtin_amdgcn_mfma_f32_16x16x32_bf16(x1, bb, a1, 0, 0, 0);
    }
    if (g == 2){                       // V -> natural layout [b][row][300]
      if (valid){
        float bias = bv[colc];
        #pragma unroll
        for (int i = 0; i < 4; ++i){
          int r0 = rh*32 + lg*4 + i;
          if (r0 < SS) vg[((size_t)b*SS + r0)*300 + col] = (short)f2bf(a0[i]+bias);
          int r1 = rh*32 + 16 + lg*4 + i;
          if (r1 < SS) vg[((size_t)b*SS + r1)*300 + col] = (short)f2bf(a1[i]+bias);
        }
      }
    } else if (g != 3){                // Qc/Qp -> [b][row][head*48 + (0|20) + dd]
      if (valid){
        float bias = (g==0) ? bq[colc] : bqp[colc];
        size_t qoff = (size_t)head*48 + dd + (g==1 ? 20 : 0);
        #pragma unroll
        for (int i = 0; i < 4; ++i){
          int r0 = rh*32 + lg*4 + i;
          if (r0 < SS) qg[((size_t)b*SS + r0)*720 + qoff] = (short)f2bf(a0[i]+bias);
          int r1 = rh*32 + 16 + lg*4 + i;
          if (r1 < SS) qg[((size_t)b*SS + r1)*720 + qoff] = (short)f2bf(a1[i]+bias);
        }
      }
    } else {                           // K: Kc at +20, then continue -> Ksum at +0
      float bkc = bk[colc];
      if (valid){
        size_t koff = (size_t)head*48 + 20 + dd;
        #pragma unroll
        for (int i = 0; i < 4; ++i){
          int r0 = rh*32 + lg*4 + i;
          if (r0 < SS) kg[((size_t)b*SS + r0)*720 + koff] = (short)f2bf(a0[i]+bkc);
          int r1 = rh*32 + 16 + lg*4 + i;
          if (r1 < SS) kg[((size_t)b*SS + r1)*720 + koff] = (short)f2bf(a1[i]+bkc);
        }
      }
      const short* wb2 = wkpT + (size_t)col*320 + lg*8;
      #pragma unroll
      for (int st = 0; st < 10; ++st){
        bf8t bb = *(const bf8t*)(wb2 + st*32);
        bf8t x0 = *(const bf8t*)(sm + K1_UE + (unsigned)(rh*32 + lm)*656u + (unsigned)(st*32 + lg*8)*2u);
        bf8t x1 = *(const bf8t*)(sm + K1_UE + (unsigned)(rh*32 + 16 + lm)*656u + (unsigned)(st*32 + lg*8)*2u);
        a0 = __builtin_amdgcn_mfma_f32_16x16x32_bf16(x0, bb, a0, 0, 0, 0);
        a1 = __builtin_amdgcn_mfma_f32_16x16x32_bf16(x1, bb, a1, 0, 0, 0);
      }
      if (valid){
        float bsum = bkc + bkp[colc];
        size_t koff = (size_t)head*48 + dd;
        #pragma unroll
        for (int i = 0; i < 4; ++i){
          int r0 = rh*32 + lg*4 + i;
          if (r0 < SS) kg[((size_t)b*SS + r0)*720 + koff] = (short)f2bf(a0[i]+bsum);
          int r1 = rh*32 + 16 + lg*4 + i;
          if (r1 < SS) kg[((size_t)b*SS + r1)*720 + koff] = (short)f2bf(a1[i]+bsum);
        }
      }
    }
  }
}

// ============================ K2: attention ==================================
// block = (b, head-group hg of <=4 heads). LDS:
//   Q [50][192]bf16 stride400 @0 ; K @20000 ; VT [92][64keys]bf16 stride144 @40000
//   P overlays Q/K: per-wave [32][64] stride144 @ w*4608
#define A_Q   0
#define A_K   20000
#define A_VT  40000
#define A_PBLK 4608
#define A_SM  53248

__global__ __launch_bounds__(512) void k2_attn(
    const short* __restrict__ qg, const short* __restrict__ kg,
    const short* __restrict__ vg, short* __restrict__ cg)
{
  __shared__ __align__(16) unsigned char sm[A_SM];
  const int tid  = threadIdx.x;
  const int bid  = blockIdx.x;
  const int b    = bid >> 2;
  const int hg   = bid & 3;
  const int nheads = (hg < 3) ? 4 : 3;
  const int w    = tid >> 6;
  const int lane = tid & 63;
  const int l31  = lane & 31, hi = lane >> 5;

  // zero VT (keys>=50 must be 0; rows 80..91 finite)
  for (int i = tid; i < 828; i += 512)
    *(float4*)(sm + A_VT + (unsigned)i*16) = make_float4(0.f,0.f,0.f,0.f);
  __syncthreads();
  // stage Q,K rows (24 float4 per row)
  for (int i = tid; i < 2400; i += 512){
    int arr = (i < 1200) ? 0 : 1;
    int j = i - arr*1200;
    int row = j/24, c = j - row*24;
    const short* src = (arr ? kg : qg) + ((size_t)b*SS + row)*720 + hg*192 + c*8;
    float4 v = *(const float4*)src;
    *(float4*)(sm + (arr ? A_K : A_Q) + (unsigned)row*400 + (unsigned)c*16) = v;
  }
  // stage VT (transpose): read u32 (2 dims) per (row,d2)
  for (int i = tid; i < 2000; i += 512){
    int row = i/40, d2 = i - row*40;
    unsigned v = *(const unsigned*)(vg + ((size_t)b*SS + row)*300 + hg*80 + d2*2);
    *(unsigned short*)(sm + A_VT + (unsigned)(d2*2)*144   + (unsigned)row*2) = (unsigned short)(v & 0xffffu);
    *(unsigned short*)(sm + A_VT + (unsigned)(d2*2+1)*144 + (unsigned)row*2) = (unsigned short)(v >> 16);
  }
  __syncthreads();

  const float rscale = 0.1290994449f;  // 1/sqrt(3*DK)
  const int ahl = w >> 1, rt = w & 1;
  const bool act = (ahl < nheads);
  f16t s0, s1;
  if (act){
    s0 = zero16(); s1 = zero16();
    unsigned aoff = A_Q + (unsigned)(rt*32 + l31)*400 + (unsigned)ahl*96 + (unsigned)hi*16;
    unsigned koff = A_K + (unsigned)l31*400 + (unsigned)ahl*96 + (unsigned)hi*16;
    #pragma unroll
    for (int ks = 0; ks < 3; ++ks){
      bf8t a  = *(const bf8t*)(sm + aoff + ks*32);
      bf8t b0 = *(const bf8t*)(sm + koff + ks*32);
      bf8t b1 = *(const bf8t*)(sm + koff + 32u*400 + ks*32);
      s0 = __builtin_amdgcn_mfma_f32_32x32x16_bf16(a, b0, s0, 0, 0, 0);
      s1 = __builtin_amdgcn_mfma_f32_32x32x16_bf16(a, b1, s1, 0, 0, 0);
    }
  }
  __syncthreads();   // Q/K reads done -> P may overwrite
  if (act){
    const bool m1 = (l31 >= 18);   // key 32+l31 >= 50
    unsigned pb = (unsigned)w*A_PBLK;
    float rinv[16];
    #pragma unroll
    for (int r = 0; r < 16; ++r){
      int lrow = (r&3) + 8*(r>>2) + 4*hi;
      float v0 = s0[r]*rscale;
      float v1 = m1 ? -INFINITY : s1[r]*rscale;
      float mx = fmaxf(v0, v1);
      #pragma unroll
      for (int off = 1; off <= 16; off <<= 1) mx = fmaxf(mx, __shfl_xor(mx, off));
      float e0 = __expf(v0 - mx);
      float e1 = m1 ? 0.f : __expf(v1 - mx);
      float sum = e0 + e1;
      #pragma unroll
      for (int off = 1; off <= 16; off <<= 1) sum += __shfl_xor(sum, off);
      rinv[r] = 1.0f/sum;
      *(unsigned short*)(sm + pb + (unsigned)lrow*144 + (unsigned)l31*2)      = f2bf(e0);
      *(unsigned short*)(sm + pb + (unsigned)lrow*144 + 64 + (unsigned)l31*2) = f2bf(e1);
    }
    f16t c = zero16();
    unsigned pa  = pb + (unsigned)l31*144 + (unsigned)hi*16;
    unsigned vb2 = A_VT + (unsigned)(ahl*HD + l31)*144 + (unsigned)hi*16;
    #pragma unroll
    for (int ks = 0; ks < 4; ++ks){
      bf8t a = *(const bf8t*)(sm + pa + ks*32);
      bf8t v = *(const bf8t*)(sm + vb2 + ks*32);
      c = __builtin_amdgcn_mfma_f32_32x32x16_bf16(a, v, c, 0, 0, 0);
    }
    if (l31 < HD){
      int h = hg*4 + ahl;
      #pragma unroll
      for (int r = 0; r < 16; ++r){
        int q = rt*32 + (r&3) + 8*(r>>2) + 4*hi;
        if (q < SS)
          cg[((size_t)b*SS + q)*300 + h*HD + l31] = (short)f2bf(c[r]*rinv[r]);
      }
    }
  }
}

// ============================ K3: pooling ====================================
// LDS: ctx bf16 [64 rows][328] stride656 @0 (rows>=50 garbage, discarded);
//      lg2d f32 [50][8] @41984; a f32[64] @44032
#define B_CTX 0
#define B_LG  41984
#define B_A2  44032
#define B_SM  44288

__global__ __launch_bounds__(512) void k3_pool(
    const short* __restrict__ cg, const short* __restrict__ wsb,
    const float* __restrict__ ba, const float* __restrict__ qa,
    float* __restrict__ out)
{
  __shared__ __align__(16) unsigned char sm[B_SM];
  const int tid  = threadIdx.x;
  const int b    = blockIdx.x;
  const int w    = tid >> 6;
  const int lane = tid & 63;
  const int lm   = lane & 15, lg = lane >> 4;
  const short* waT = wsb + WAOFF;

  // stage ctx: uint2 = 4 bf16 per iter; 75 iters/row * 4 = 300 elements/row (FIX)
  for (int i = tid; i < SS*75; i += 512){
    int row = i/75, c = i - row*75;
    uint2 v = *(const uint2*)(cg + ((size_t)b*SS + row)*300 + c*4);
    *(uint2*)(sm + B_CTX + (unsigned)row*656 + (unsigned)c*8) = v;
  }
  for (int i = tid; i < SS*14; i += 512)
    *(unsigned*)(sm + B_CTX + (unsigned)(i/14)*656 + 600u + (unsigned)(i%14)*4) = 0;
  __syncthreads();

  {
    f4t accp[2][4];
    #pragma unroll
    for (int t = 0; t < 2; ++t)
      #pragma unroll
      for (int r = 0; r < 4; ++r) accp[t][r] = (f4t){0.f,0.f,0.f,0.f};
    gemm10<2,12>(sm, B_CTX, waT, lane, w, accp);
    float part[4][4];
    #pragma unroll
    for (int rt2 = 0; rt2 < 4; ++rt2)
      #pragma unroll
      for (int i = 0; i < 4; ++i) part[rt2][i] = 0.f;
    #pragma unroll
    for (int t = 0; t < 2; ++t){
      int ct = w + t*8; if (ct > 12) ct = 12;
      bool valid = (t == 0) || (w < 5);
      int col = ct*16 + lm;
      float bav = (col < QDIM) ? ba[col] : 0.f;
      float qav = (valid && col < QDIM) ? qa[col] : 0.f;
      #pragma unroll
      for (int rt2 = 0; rt2 < 4; ++rt2)
        #pragma unroll
        for (int i = 0; i < 4; ++i)
          part[rt2][i] += tanhf(accp[t][rt2][i] + bav) * qav;
    }
    #pragma unroll
    for (int off = 1; off <= 8; off <<= 1)
      #pragma unroll
      for (int rt2 = 0; rt2 < 4; ++rt2)
        #pragma unroll
        for (int i = 0; i < 4; ++i)
          part[rt2][i] += __shfl_xor(part[rt2][i], off);
    if (lm == 0){
      #pragma unroll
      for (int rt2 = 0; rt2 < 4; ++rt2)
        #pragma unroll
        for (int i = 0; i < 4; ++i){
          int row = rt2*16 + lg*4 + i;
          if (row < SS) *(float*)(sm + B_LG + (unsigned)(row*8 + w)*4) = part[rt2][i];
        }
    }
  }
  __syncthreads();
  if (w == 0){
    const int sl = lane < SS ? lane : SS - 1;
    const bool rowok = lane < SS;
    float lgv = -INFINITY;
    if (rowok){
      float s = 0.f;
      #pragma unroll
      for (int j = 0; j < 8; ++j) s += *(const float*)(sm + B_LG + (unsigned)(sl*8 + j)*4);
      lgv = s;
    }
    float m = lgv;
    #pragma unroll
    for (int off = 32; off; off >>= 1) m = fmaxf(m, __shfl_xor(m, off));
    float e = rowok ? __expf(lgv - m) : 0.f;
    float ssum = e;
    #pragma unroll
    for (int off = 32; off; off >>= 1) ssum += __shfl_xor(ssum, off);
    *(float*)(sm + B_A2 + lane*4) = e / ssum;
  }
  __syncthreads();
  if (tid < DD){
    float accv = 0.f;
    for (int s = 0; s < SS; ++s){
      float av = *(const float*)(sm + B_A2 + (unsigned)s*4);
      unsigned short cv = *(const unsigned short*)(sm + B_CTX + (unsigned)s*656 + (unsigned)tid*2);
      accv = fmaf(av, __uint_as_float((unsigned)cv << 16), accv);
    }
    out[(size_t)b*DD + tid] = accv;
  }
}

// ===================== fallback: round-4 fused kernel ========================
#define OFF_UV  0
#define OFF_UE  32800
#define QKSTR   400
#define OFF_Q   65600
#define OFF_K   85600
#define OFF_P   65600
#define PBLK    4608
#define PSTR    144
#define VTSTR   144
#define OFF_VT  105600
#define OFF_CTX 117120
#define OFF_LG  159104
#define OFF_A2  161152
#define OFF_IDS 161408
#define SM_TOTAL 161616

__global__ __launch_bounds__(512) void user_enc_kernel(
    const int*   __restrict__ ids, const float* __restrict__ uv,
    const float* __restrict__ emb,
    const float* __restrict__ bq, const float* __restrict__ bk,
    const float* __restrict__ bv, const float* __restrict__ bqp,
    const float* __restrict__ bkp,
    const float* __restrict__ ba, const float* __restrict__ qa,
    const short* __restrict__ wsb, float* __restrict__ out)
{
  __shared__ __align__(16) unsigned char sm[SM_TOTAL];
  const int tid  = threadIdx.x;
  const int b    = blockIdx.x;
  const int w    = tid >> 6;
  const int lane = tid & 63;
  const int lm   = lane & 15, lg = lane >> 4;
  const int l31  = lane & 31, hi = lane >> 5;

  const short* wqT  = wsb;
  const short* wkT  = wsb + WSEG;
  const short* wvT  = wsb + 2*WSEG;
  const short* wqpT = wsb + 3*WSEG;
  const short* wkpT = wsb + 4*WSEG;
  const short* waT  = wsb + WAOFF;

  if (tid < SS) *(int*)(sm + OFF_IDS + tid*4) = ids[(size_t)b*SS + tid];
  {
    const float* srcv = uv + (size_t)b*SS*DD;
    for (int i = tid; i < SS*75; i += 512){
      int s = i/75, j4 = i - s*75;
      float4 v = *(const float4*)(srcv + s*DD + j4*4);
      *(unsigned*)(sm + OFF_UV + (unsigned)s*656 + (unsigned)j4*8)     = packbf(v.x, v.y);
      *(unsigned*)(sm + OFF_UV + (unsigned)s*656 + (unsigned)j4*8 + 4) = packbf(v.z, v.w);
    }
    for (int i = tid; i < SS*28; i += 512){
      int s = i/28, j = i - s*28;
      unsigned off = (j < 14) ? (OFF_UV + (unsigned)s*656 + 600u + (unsigned)j*4)
                              : (OFF_UE + (unsigned)s*656 + 600u + (unsigned)(j-14)*4);
      *(unsigned*)(sm + off) = 0;
    }
    for (int i = tid; i < SS*14; i += 512)
      *(unsigned*)(sm + OFF_CTX + (unsigned)(i/14)*656 + 600u + (unsigned)(i%14)*4) = 0;
    for (int i = tid; i < 720; i += 512)
      *(float4*)(sm + OFF_VT + (unsigned)i*16) = make_float4(0.f,0.f,0.f,0.f);
  }
  __syncthreads();
  for (int i = tid; i < SS*75; i += 512){
    int s = i/75, j4 = i - s*75;
    int id = *(const int*)(sm + OFF_IDS + s*4);
    float4 v = *(const float4*)(emb + (size_t)id*DD + j4*4);
    *(unsigned*)(sm + OFF_UE + (unsigned)s*656 + (unsigned)j4*8)     = packbf(v.x, v.y);
    *(unsigned*)(sm + OFF_UE + (unsigned)s*656 + (unsigned)j4*8 + 4) = packbf(v.z, v.w);
  }

  const float rscale = 0.1290994449f;
  #pragma unroll 1
  for (int nb4 = 0; nb4 < 4; ++nb4){
    const int nheads = (nb4 < 3) ? 4 : 3;
    const int NCT    = (nb4 < 3) ? 5 : 4;
    __syncthreads();
    for (int i = tid; i < SS*4; i += 512){
      int r = i >> 2, hl0 = i & 3;
      *(float4*)(sm + OFF_Q + (unsigned)r*QKSTR + (unsigned)hl0*96 + 80) = make_float4(0.f,0.f,0.f,0.f);
      *(float4*)(sm + OFF_K + (unsigned)r*QKSTR + (unsigned)hl0*96 + 80) = make_float4(0.f,0.f,0.f,0.f);
    }
    for (int ht = w; ht < 8*NCT; ht += 8){
      const int g   = (ht >= 6*NCT) ? 3 : (ht >= 4*NCT) ? 2 : (ht >= 2*NCT) ? 1 : 0;
      const int rem = ht - g*2*NCT;
      const int c   = rem >> 1, rh = rem & 1;
      const int col = nb4*80 + c*16 + lm;
      const int colc = (col < DD) ? col : DD-1;
      const int head = col / HD;
      const int dd   = col - head*HD;
      const int hl   = head - nb4*4;
      const bool valid = (hl < nheads) && (col < DD);
      const unsigned abase = (g == 1) ? (unsigned)OFF_UE : (unsigned)OFF_UV;
      const short* wt = (g==0) ? wqT : (g==1) ? wqpT : (g==2) ? wvT : wkT;
      const short* wb = wt + (size_t)col*320 + lg*8;
      f4t a0 = {0.f,0.f,0.f,0.f}, a1 = {0.f,0.f,0.f,0.f};
      #pragma unroll
      for (int st = 0; st < 10; ++st){
        bf8t bb = *(const bf8t*)(wb + st*32);
        bf8t x0 = *(const bf8t*)(sm + abase + (unsigned)(rh*32 + lm)*656u + (unsigned)(st*32 + lg*8)*2u);
        bf8t x1 = *(const bf8t*)(sm + abase + (unsigned)(rh*32 + 16 + lm)*656u + (unsigned)(st*32 + lg*8)*2u);
        a0 = __builtin_amdgcn_mfma_f32_16x16x32_bf16(x0, bb, a0, 0, 0, 0);
        a1 = __builtin_amdgcn_mfma_f32_16x16x32_bf16(x1, bb, a1, 0, 0, 0);
      }
      if (g == 2){
        if (valid){
          float bias = bv[colc];
          unsigned vb = OFF_VT + (unsigned)(hl*HD + dd)*VTSTR;
          int r0 = rh*32 + lg*4;
          if (r0 < SS){
            *(unsigned*)(sm + vb + (unsigned)r0*2) = packbf(a0[0]+bias, a0[1]+bias);
            if (r0+2 < SS) *(unsigned*)(sm + vb + (unsigned)r0*2 + 4) = packbf(a0[2]+bias, a0[3]+bias);
          }
          int r1 = rh*32 + 16 + lg*4;
          if (r1 < SS){
            *(unsigned*)(sm + vb + (unsigned)r1*2) = packbf(a1[0]+bias, a1[1]+bias);
            if (r1+2 < SS) *(unsigned*)(sm + vb + (unsigned)r1*2 + 4) = packbf(a1[2]+bias, a1[3]+bias);
          }
        }
      } else if (g != 3){
        if (valid){
          float bias = (g==0) ? bq[colc] : bqp[colc];
          unsigned qb = OFF_Q + (unsigned)hl*96 + (unsigned)dd*2 + (g==1 ? 40u : 0u);
          #pragma unroll
          for (int i = 0; i < 4; ++i){
            int r0 = rh*32 + lg*4 + i;
            if (r0 < SS) *(unsigned short*)(sm + qb + (unsigned)r0*QKSTR) = f2bf(a0[i]+bias);
            int r1 = rh*32 + 16 + lg*4 + i;
            if (r1 < SS) *(unsigned short*)(sm + qb + (unsigned)r1*QKSTR) = f2bf(a1[i]+bias);
          }
        }
      } else {
        float bkc = bk[colc];
        if (valid){
          unsigned kb = OFF_K + (unsigned)hl*96 + (unsigned)dd*2 + 40u;
          #pragma unroll
          for (int i = 0; i < 4; ++i){
            int r0 = rh*32 + lg*4 + i;
            if (r0 < SS) *(unsigned short*)(sm + kb + (unsigned)r0*QKSTR) = f2bf(a0[i]+bkc);
            int r1 = rh*32 + 16 + lg*4 + i;
            if (r1 < SS) *(unsigned short*)(sm + kb + (unsigned)r1*QKSTR) = f2bf(a1[i]+bkc);
          }
        }
        const short* wb2 = wkpT + (size_t)col*320 + lg*8;
        #pragma unroll
        for (int st = 0; st < 10; ++st){
          bf8t bb = *(const bf8t*)(wb2 + st*32);
          bf8t x0 = *(const bf8t*)(sm + OFF_UE + (unsigned)(rh*32 + lm)*656u + (unsigned)(st*32 + lg*8)*2u);
          bf8t x1 = *(const bf8t*)(sm + OFF_UE + (unsigned)(rh*32 + 16 + lm)*656u + (unsigned)(st*32 + lg*8)*2u);
          a0 = __builtin_amdgcn_mfma_f32_16x16x32_bf16(x0, bb, a0, 0, 0, 0);
          a1 = __builtin_amdgcn_mfma_f32_16x16x32_bf16(x1, bb, a1, 0, 0, 0);
        }
        if (valid){
          float bsum = bkc + bkp[colc];
          unsigned kb = OFF_K + (unsigned)hl*96 + (unsigned)dd*2;
          #pragma unroll
          for (int i = 0; i < 4; ++i){
            int r0 = rh*32 + lg*4 + i;
            if (r0 < SS) *(unsigned short*)(sm + kb + (unsigned)r0*QKSTR) = f2bf(a0[i]+bsum);
            int r1 = rh*32 + 16 + lg*4 + i;
            if (r1 < SS) *(unsigned short*)(sm + kb + (unsigned)r1*QKSTR) = f2bf(a1[i]+bsum);
          }
        }
      }
    }
    __syncthreads();
    const int ahl = w >> 1, rt = w & 1;
    const bool act = (ahl < nheads);
    f16t s0, s1;
    if (act){
      s0 = zero16(); s1 = zero16();
      unsigned aoff = OFF_Q + (unsigned)(rt*32 + l31)*QKSTR + (unsigned)ahl*96 + (unsigned)hi*16;
      unsigned koff = OFF_K + (unsigned)l31*QKSTR + (unsigned)ahl*96 + (unsigned)hi*16;
      #pragma unroll
      for (int ks = 0; ks < 3; ++ks){
        bf8t a  = *(const bf8t*)(sm + aoff + ks*32);
        bf8t b0 = *(const bf8t*)(sm + koff + ks*32);
        bf8t b1 = *(const bf8t*)(sm + koff + 32u*QKSTR + ks*32);
        s0 = __builtin_amdgcn_mfma_f32_32x32x16_bf16(a, b0, s0, 0, 0, 0);
        s1 = __builtin_amdgcn_mfma_f32_32x32x16_bf16(a, b1, s1, 0, 0, 0);
      }
    }
    __syncthreads();
    if (act){
      const bool m1 = (l31 >= 18);
      unsigned pb = OFF_P + (unsigned)w*PBLK;
      float rinv[16];
      #pragma unroll
      for (int r = 0; r < 16; ++r){
        int lrow = (r&3) + 8*(r>>2) + 4*hi;
        float v0 = s0[r]*rscale;
        float v1 = m1 ? -INFINITY : s1[r]*rscale;
        float mx = fmaxf(v0, v1);
        #pragma unroll
        for (int off = 1; off <= 16; off <<= 1) mx = fmaxf(mx, __shfl_xor(mx, off));
        float e0 = __expf(v0 - mx);
        float e1 = m1 ? 0.f : __expf(v1 - mx);
        float sum = e0 + e1;
        #pragma unroll
        for (int off = 1; off <= 16; off <<= 1) sum += __shfl_xor(sum, off);
        rinv[r] = 1.0f/sum;
        *(unsigned short*)(sm + pb + (unsigned)lrow*PSTR + (unsigned)l31*2)      = f2bf(e0);
        *(unsigned short*)(sm + pb + (unsigned)lrow*PSTR + 64 + (unsigned)l31*2) = f2bf(e1);
      }
      f16t c = zero16();
      unsigned pa  = pb + (unsigned)l31*PSTR + (unsigned)hi*16;
      unsigned vb2 = OFF_VT + (unsigned)(ahl*HD + l31)*VTSTR + (unsigned)hi*16;
      #pragma unroll
      for (int ks = 0; ks < 4; ++ks){
        bf8t a = *(const bf8t*)(sm + pa + ks*32);
        bf8t v = *(const bf8t*)(sm + vb2 + ks*32);
        c = __builtin_amdgcn_mfma_f32_32x32x16_bf16(a, v, c, 0, 0, 0);
      }
      if (l31 < HD){
        int h = nb4*4 + ahl;
        #pragma unroll
        for (int r = 0; r < 16; ++r){
          int q = rt*32 + (r&3) + 8*(r>>2) + 4*hi;
          if (q < SS)
            *(unsigned short*)(sm + OFF_CTX + (unsigned)q*656 + (unsigned)(h*HD + l31)*2) =
                f2bf(c[r]*rinv[r]);
        }
      }
    }
  }
  __syncthreads();

  {
    f4t accp[2][4];
    #pragma unroll
    for (int t = 0; t < 2; ++t)
      #pragma unroll
      for (int r = 0; r < 4; ++r) accp[t][r] = (f4t){0.f,0.f,0.f,0.f};
    gemm10<2,12>(sm, OFF_CTX, waT, lane, w, accp);
    float part[4][4];
    #pragma unroll
    for (int rt2 = 0; rt2 < 4; ++rt2)
      #pragma unroll
      for (int i = 0; i < 4; ++i) part[rt2][i] = 0.f;
    #pragma unroll
    for (int t = 0; t < 2; ++t){
      int ct = w + t*8; if (ct > 12) ct = 12;
      bool valid = (t == 0) || (w < 5);
      int col = ct*16 + lm;
      float bav = (col < QDIM) ? ba[col] : 0.f;
      float qav = (valid && col < QDIM) ? qa[col] : 0.f;
      #pragma unroll
      for (int rt2 = 0; rt2 < 4; ++rt2)
        #pragma unroll
        for (int i = 0; i < 4; ++i)
          part[rt2][i] += tanhf(accp[t][rt2][i] + bav) * qav;
    }
    #pragma unroll
    for (int off = 1; off <= 8; off <<= 1)
      #pragma unroll
      for (int rt2 = 0; rt2 < 4; ++rt2)
        #pragma unroll
        for (int i = 0; i < 4; ++i)
          part[rt2][i] += __shfl_xor(part[rt2][i], off);
    if (lm == 0){
      #pragma unroll
      for (int rt2 = 0; rt2 < 4; ++rt2)
        #pragma unroll
        for (int i = 0; i < 4; ++i){
          int row = rt2*16 + lg*4 + i;
          if (row < SS) *(float*)(sm + OFF_LG + (unsigned)(row*8 + w)*4) = part[rt2][i];
        }
    }
  }
  __syncthreads();
  if (w == 0){
    const int sl = lane < SS ? lane : SS - 1;
    const bool rowok = lane < SS;
    float lgv = -INFINITY;
    if (rowok){
      float s = 0.f;
      #pragma unroll
      for (int j = 0; j < 8; ++j) s += *(const float*)(sm + OFF_LG + (unsigned)(sl*8 + j)*4);
      lgv = s;
    }
    float m = lgv;
    #pragma unroll
    for (int off = 32; off; off >>= 1) m = fmaxf(m, __shfl_xor(m, off));
    float e = rowok ? __expf(lgv - m) : 0.f;
    float ssum = e;
    #pragma unroll
    for (int off = 32; off; off >>= 1) ssum += __shfl_xor(ssum, off);
    *(float*)(sm + OFF_A2 + lane*4) = e / ssum;
  }
  __syncthreads();
  if (tid < DD){
    float accv = 0.f;
    for (int s = 0; s < SS; ++s){
      float av = *(const float*)(sm + OFF_A2 + (unsigned)s*4);
      unsigned short cv = *(const unsigned short*)(sm + OFF_CTX + (unsigned)s*656 + (unsigned)tid*2);
      accv = fmaf(av, __uint_as_float((unsigned)cv << 16), accv);
    }
    out[(size_t)b*DD + tid] = accv;
  }
}

extern "C" void kernel_launch(void* const* d_in, const int* in_sizes, int n_in,
                              void* d_out, int out_size, void* d_ws, size_t ws_size,
                              hipStream_t stream){
  (void)n_in; (void)out_size;
  const int*   ids = (const int*)  d_in[0];
  const float* uvp = (const float*)d_in[1];
  const float* emb = (const float*)d_in[2];
  const float* Wq  = (const float*)d_in[3];
  const float* bq  = (const float*)d_in[4];
  const float* Wk  = (const float*)d_in[5];
  const float* bk  = (const float*)d_in[6];
  const float* Wv  = (const float*)d_in[7];
  const float* bv  = (const float*)d_in[8];
  const float* Wqp = (const float*)d_in[9];
  const float* bqp = (const float*)d_in[10];
  const float* Wkp = (const float*)d_in[11];
  const float* bkp = (const float*)d_in[12];
  const float* Wa  = (const float*)d_in[13];
  const float* ba  = (const float*)d_in[14];
  const float* qa  = (const float*)d_in[15];
  short* wsb = (short*)d_ws;

  const int nb = in_sizes[0] / SS;   // 1024
  const size_t wbytes = (size_t)WTOT * 2;
  const size_t qelems = (size_t)nb * SS * 720;
  const size_t velems = (size_t)nb * SS * 300;
  const size_t need   = wbytes + 2*qelems*2 + 2*velems*2;

  conv_weights<<<(WTOT + 255)/256, 256, 0, stream>>>(Wq, Wk, Wv, Wqp, Wkp, Wa, wsb);

  if (ws_size >= need){
    short* qg = (short*)((char*)d_ws + wbytes);
    short* kg = qg + qelems;
    short* vg = kg + qelems;
    short* cg = vg + velems;
    k1_proj<<<nb, 512, 0, stream>>>(ids, uvp, emb, bq, bk, bv, bqp, bkp,
                                    (const short*)wsb, qg, kg, vg);
    k2_attn<<<nb*4, 512, 0, stream>>>((const short*)qg, (const short*)kg,
                                      (const short*)vg, cg);
    k3_pool<<<nb, 512, 0, stream>>>((const short*)cg, (const short*)wsb,
                                    ba, qa, (float*)d_out);
  } else {
    user_enc_kernel<<<nb, 512, 0, stream>>>(ids, uvp, emb,
                                            bq, bk, bv, bqp, bkp, ba, qa,
                                            (const short*)wsb, (float*)d_out);
  }
}